// Round 1
// baseline (2643.302 us; speedup 1.0000x reference)
//
#include <hip/hip_runtime.h>
#include <cstdint>

#define NN 65536
#define EE 524288
#define BS_ 16

// ---------------- threefry2x32 (JAX-compatible, key = (0,42)) ----------------
__device__ __forceinline__ uint32_t rotl32(uint32_t x, int d) {
    return (x << d) | (x >> (32 - d));
}
__device__ __forceinline__ void threefry_0_42(uint32_t& x0, uint32_t& x1) {
    const uint32_t ks0 = 0u, ks1 = 42u, ks2 = 0u ^ 42u ^ 0x1BD11BDAu;
    x0 += ks0; x1 += ks1;
#define RND(r) { x0 += x1; x1 = rotl32(x1, r); x1 ^= x0; }
    RND(13) RND(15) RND(26) RND(6)  x0 += ks1; x1 += ks2 + 1u;
    RND(17) RND(29) RND(16) RND(24) x0 += ks2; x1 += ks0 + 2u;
    RND(13) RND(15) RND(26) RND(6)  x0 += ks0; x1 += ks1 + 3u;
    RND(17) RND(29) RND(16) RND(24) x0 += ks1; x1 += ks2 + 4u;
    RND(13) RND(15) RND(26) RND(6)  x0 += ks2; x1 += ks0 + 5u;
#undef RND
}

// ---------------- graph preprocessing ----------------
__global__ void k_indeg(const int* __restrict__ dst, int* __restrict__ indeg) {
    int e = blockIdx.x * 256 + threadIdx.x;
    if (e < EE) atomicAdd(&indeg[dst[e]], 1);
}

// single block, 256 threads; each thread scans 256 contiguous nodes
__global__ void k_scan(const int* __restrict__ indeg, int* __restrict__ rowptr,
                       int* __restrict__ cursor) {
    __shared__ int psum[256];
    int t = threadIdx.x;
    int base = t * 256;
    int s = 0;
    for (int i = 0; i < 256; ++i) s += indeg[base + i];
    psum[t] = s;
    __syncthreads();
    for (int off = 1; off < 256; off <<= 1) {
        int v = (t >= off) ? psum[t - off] : 0;
        __syncthreads();
        psum[t] += v;
        __syncthreads();
    }
    int run = (t == 0) ? 0 : psum[t - 1];
    for (int i = 0; i < 256; ++i) {
        rowptr[base + i] = run;
        cursor[base + i] = run;
        run += indeg[base + i];
    }
    if (t == 255) rowptr[NN] = run;
}

__global__ void k_fill(const int* __restrict__ src, const int* __restrict__ dst,
                       int* __restrict__ cursor, int* __restrict__ csr) {
    int e = blockIdx.x * 256 + threadIdx.x;
    if (e < EE) {
        int d = dst[e];
        int p = atomicAdd(&cursor[d], 1);
        csr[p] = src[e];
    }
}

__global__ void k_dinv(const int* __restrict__ indeg, float* __restrict__ dinv) {
    int i = blockIdx.x * 256 + threadIdx.x;
    if (i < NN) dinv[i] = rsqrtf((float)indeg[i] + 1.0f);
}

// ---------------- generic fp32 tiled GEMM: C = A[M,K] @ W[K,N] (+bias) (+C) ----------------
#define BM 64
#define BN 64
#define BK 16

template <bool ACC, bool BIAS>
__global__ __launch_bounds__(256) void k_gemm(const float* __restrict__ A,
                                              const float* __restrict__ W,
                                              const float* __restrict__ bias,
                                              float* __restrict__ C,
                                              int M, int K, int N) {
    __shared__ float As[BK][BM + 4];
    __shared__ float Ws[BK][BN];
    int tid = threadIdx.x;
    int bm = blockIdx.x * BM;
    int bn = blockIdx.y * BN;
    int tx = tid & 15, ty = tid >> 4;
    int arow = tid >> 2;            // 0..63
    int acolq = (tid & 3) * 4;      // 0,4,8,12
    int wrow = tid >> 4;            // 0..15
    int wcolq = (tid & 15) * 4;     // 0..60

    float acc[4][4];
#pragma unroll
    for (int i = 0; i < 4; ++i)
#pragma unroll
        for (int j = 0; j < 4; ++j) acc[i][j] = 0.f;

    for (int k0 = 0; k0 < K; k0 += BK) {
        const float* Ap = A + (size_t)(bm + arow) * K + k0 + acolq;
#pragma unroll
        for (int j = 0; j < 4; ++j) {
            int kk = k0 + acolq + j;
            As[acolq + j][arow] = (kk < K) ? Ap[j] : 0.f;
        }
        int kk = k0 + wrow;
        const float* Wp = W + (size_t)kk * N + bn + wcolq;
#pragma unroll
        for (int j = 0; j < 4; ++j) {
            int cc = bn + wcolq + j;
            Ws[wrow][wcolq + j] = (kk < K && cc < N) ? Wp[j] : 0.f;
        }
        __syncthreads();
#pragma unroll
        for (int k = 0; k < BK; ++k) {
            float a0 = As[k][ty * 4 + 0], a1 = As[k][ty * 4 + 1];
            float a2 = As[k][ty * 4 + 2], a3 = As[k][ty * 4 + 3];
            float w0 = Ws[k][tx * 4 + 0], w1 = Ws[k][tx * 4 + 1];
            float w2 = Ws[k][tx * 4 + 2], w3 = Ws[k][tx * 4 + 3];
            acc[0][0] = fmaf(a0, w0, acc[0][0]); acc[0][1] = fmaf(a0, w1, acc[0][1]);
            acc[0][2] = fmaf(a0, w2, acc[0][2]); acc[0][3] = fmaf(a0, w3, acc[0][3]);
            acc[1][0] = fmaf(a1, w0, acc[1][0]); acc[1][1] = fmaf(a1, w1, acc[1][1]);
            acc[1][2] = fmaf(a1, w2, acc[1][2]); acc[1][3] = fmaf(a1, w3, acc[1][3]);
            acc[2][0] = fmaf(a2, w0, acc[2][0]); acc[2][1] = fmaf(a2, w1, acc[2][1]);
            acc[2][2] = fmaf(a2, w2, acc[2][2]); acc[2][3] = fmaf(a2, w3, acc[2][3]);
            acc[3][0] = fmaf(a3, w0, acc[3][0]); acc[3][1] = fmaf(a3, w1, acc[3][1]);
            acc[3][2] = fmaf(a3, w2, acc[3][2]); acc[3][3] = fmaf(a3, w3, acc[3][3]);
        }
        __syncthreads();
    }
#pragma unroll
    for (int i = 0; i < 4; ++i) {
        int r = bm + ty * 4 + i;
#pragma unroll
        for (int j = 0; j < 4; ++j) {
            int c = bn + tx * 4 + j;
            if (c < N) {
                float v = acc[i][j];
                if (BIAS) v += bias[c];
                size_t idx = (size_t)r * N + c;
                if (ACC) v += C[idx];
                C[idx] = v;
            }
        }
    }
}

// ---------------- GCN aggregation: out[n] = sum_s h[s]*dinv[s]*dinv[n] + h[n]*dinv[n]^2 + b ----
template <int D>
__global__ __launch_bounds__(256) void k_gcn_agg(const float* __restrict__ h,
                                                 const int* __restrict__ rowptr,
                                                 const int* __restrict__ csr,
                                                 const float* __restrict__ dinv,
                                                 const float* __restrict__ bias,
                                                 float* __restrict__ out) {
    constexpr int NF = (D + 63) / 64;
    int lane = threadIdx.x & 63;
    int n = blockIdx.x * 4 + (threadIdx.x >> 6);
    float di = dinv[n];
    const float* hn = h + (size_t)n * D;
    float acc[NF];
#pragma unroll
    for (int j = 0; j < NF; ++j) {
        int f = lane + 64 * j;
        acc[j] = (f < D) ? hn[f] * di * di : 0.f;
    }
    int e1 = rowptr[n + 1];
    for (int e = rowptr[n]; e < e1; ++e) {
        int s = csr[e];
        float w = dinv[s] * di;
        const float* hs = h + (size_t)s * D;
#pragma unroll
        for (int j = 0; j < NF; ++j) {
            int f = lane + 64 * j;
            if (f < D) acc[j] = fmaf(hs[f], w, acc[j]);
        }
    }
    float* on = out + (size_t)n * D;
#pragma unroll
    for (int j = 0; j < NF; ++j) {
        int f = lane + 64 * j;
        if (f < D) on[f] = acc[j] + bias[f];
    }
}

// ---------------- SAGE mean aggregation ----------------
template <int D>
__global__ __launch_bounds__(256) void k_sage_mean(const float* __restrict__ x,
                                                   const int* __restrict__ rowptr,
                                                   const int* __restrict__ csr,
                                                   const int* __restrict__ indeg,
                                                   float* __restrict__ mean) {
    constexpr int NF = (D + 63) / 64;
    int lane = threadIdx.x & 63;
    int n = blockIdx.x * 4 + (threadIdx.x >> 6);
    int cnt = indeg[n];
    float inv = 1.0f / (float)(cnt > 1 ? cnt : 1);
    float acc[NF];
#pragma unroll
    for (int j = 0; j < NF; ++j) acc[j] = 0.f;
    int e1 = rowptr[n + 1];
    for (int e = rowptr[n]; e < e1; ++e) {
        int s = csr[e];
        const float* xs = x + (size_t)s * D;
#pragma unroll
        for (int j = 0; j < NF; ++j) {
            int f = lane + 64 * j;
            if (f < D) acc[j] += xs[f];
        }
    }
    float* mn = mean + (size_t)n * D;
#pragma unroll
    for (int j = 0; j < NF; ++j) {
        int f = lane + 64 * j;
        if (f < D) mn[f] = acc[j] * inv;
    }
}

// ---------------- batchnorm (leaky_relu fused) ----------------
template <int D>
__global__ __launch_bounds__(256) void k_bn_stats(const float* __restrict__ x,
                                                  float* __restrict__ stats) {
    constexpr int NC = (D + 255) / 256;
    int t = threadIdx.x;
    int r0 = blockIdx.x * 256;
    float s[NC], q[NC];
#pragma unroll
    for (int i = 0; i < NC; ++i) { s[i] = 0.f; q[i] = 0.f; }
    for (int r = r0; r < r0 + 256; ++r) {
        const float* row = x + (size_t)r * D;
#pragma unroll
        for (int i = 0; i < NC; ++i) {
            int c = t + 256 * i;
            if (c < D) {
                float v = row[c];
                v = v >= 0.f ? v : 0.01f * v;
                s[i] += v;
                q[i] += v * v;
            }
        }
    }
#pragma unroll
    for (int i = 0; i < NC; ++i) {
        int c = t + 256 * i;
        if (c < D) {
            atomicAdd(&stats[c], s[i]);
            atomicAdd(&stats[512 + c], q[i]);
        }
    }
}

template <int D>
__global__ __launch_bounds__(256) void k_bn_apply(float* __restrict__ x,
                                                  const float* __restrict__ stats) {
    const float invN = 1.0f / (float)NN;
    size_t total = (size_t)NN * D;
    size_t stride = (size_t)gridDim.x * 256;
    for (size_t idx = (size_t)blockIdx.x * 256 + threadIdx.x; idx < total; idx += stride) {
        int c = (int)(idx % D);
        float mu = stats[c] * invN;
        float ms = stats[512 + c] * invN;
        float var = ms - mu * mu;
        float v = x[idx];
        v = v >= 0.f ? v : 0.01f * v;
        x[idx] = (v - mu) * rsqrtf(var + 1e-5f);
    }
}

// ---------------- pooling: pooled[b][f] = sum over 4096 rows ----------------
__global__ __launch_bounds__(256) void k_pool(const float* __restrict__ h,
                                              float* __restrict__ pooled) {
    int b = blockIdx.x;
    int t = threadIdx.x;
    int f = t & 63, g = t >> 6;
    __shared__ float red[4][64];
    float acc = 0.f;
    if (f < 50) {
        for (int r = g; r < 4096; r += 4)
            acc += h[((size_t)b * 4096 + r) * 50 + f];
    }
    red[g][f] = acc;
    __syncthreads();
    if (g == 0 && f < 50)
        pooled[b * 50 + f] = red[0][f] + red[1][f] + red[2][f] + red[3][f];
}

// ---------------- head: attention plug + final MLP ----------------
__global__ __launch_bounds__(256) void k_head(
    const float* __restrict__ gender, const float* __restrict__ age,
    const float* __restrict__ handed, const float* __restrict__ Wq,
    const float* __restrict__ bq, const float* __restrict__ Wk,
    const float* __restrict__ bk, const float* __restrict__ Wv,
    const float* __restrict__ bv, const float* __restrict__ Wfc,
    const float* __restrict__ bfc, const float* __restrict__ Wf1,
    const float* __restrict__ bf1, const float* __restrict__ Wf2,
    const float* __restrict__ bf2, const float* __restrict__ Wf3,
    const float* __restrict__ bf3, const float* __restrict__ pooled,
    float* __restrict__ dout) {
    __shared__ float plug[BS_][8];
    __shared__ float qs[BS_][32], ks[BS_][32], vs[BS_][32];
    __shared__ float gum[256];
    __shared__ float x32[BS_][32];
    __shared__ float px[BS_][4];
    __shared__ float embs[BS_][54];
    __shared__ float t1[BS_][32];
    __shared__ float t2[BS_][16];
    int t = threadIdx.x;

    if (t < 128) {
        int b = t >> 3, c = t & 7;
        float v;
        if (c < 2) v = gender[b * 2 + c];
        else if (c == 2) v = age[b];
        else v = handed[b * 5 + (c - 3)];
        plug[b][c] = v;
    }
    // gumbel noise (threefry, key=42, shape (16,4,4) flat 256)
    {
        uint32_t lane = (uint32_t)(t & 127);
        uint32_t a = lane, b2 = lane + 128u;
        threefry_0_42(a, b2);
        uint32_t bits = (t < 128) ? a : b2;
        float u = __uint_as_float((bits >> 9) | 0x3f800000u) - 1.0f;
        const float mn = 1e-9f;
        u = u * (1.0f - mn) + mn;
        u = fmaxf(mn, u);
        gum[t] = -logf(-logf(u));
    }
    __syncthreads();
    // q,k,v
    for (int idx = t; idx < 512; idx += 256) {
        int b = idx >> 5, c = idx & 31;
        float aq = bq[c], ak = bk[c], av = bv[c];
#pragma unroll
        for (int i = 0; i < 8; ++i) {
            float p = plug[b][i];
            aq = fmaf(p, Wq[i * 32 + c], aq);
            ak = fmaf(p, Wk[i * 32 + c], ak);
            av = fmaf(p, Wv[i * 32 + c], av);
        }
        qs[b][c] = aq; ks[b][c] = ak; vs[b][c] = av;
    }
    __syncthreads();
    // scores + gumbel softmax + PV
    if (t < 64) {
        int b = t >> 2, h = t & 3;
        const float isq = 0.35355339059327373f;  // 1/sqrt(8)
        const float sq = 2.8284271247461903f;    // sqrt(8)
        float sc[4];
#pragma unroll
        for (int j = 0; j < 4; ++j) {
            float d = 0.f;
#pragma unroll
            for (int dd = 0; dd < 8; ++dd) d = fmaf(qs[b][h * 8 + dd], ks[b][j * 8 + dd], d);
            sc[j] = d * isq + gum[b * 16 + h * 4 + j];
        }
        float m = fmaxf(fmaxf(sc[0], sc[1]), fmaxf(sc[2], sc[3]));
        float e0 = expf(sc[0] - m), e1 = expf(sc[1] - m), e2 = expf(sc[2] - m), e3 = expf(sc[3] - m);
        float sum = e0 + e1 + e2 + e3;
        float a0 = e0 / sum * sq, a1 = e1 / sum * sq, a2 = e2 / sum * sq, a3 = e3 / sum * sq;
#pragma unroll
        for (int dd = 0; dd < 8; ++dd) {
            float o = a0 * vs[b][0 * 8 + dd] + a1 * vs[b][1 * 8 + dd] +
                      a2 * vs[b][2 * 8 + dd] + a3 * vs[b][3 * 8 + dd];
            x32[b][h * 8 + dd] = o;
        }
    }
    __syncthreads();
    // plugx = x32 @ Wfc + bfc
    if (t < 64) {
        int b = t >> 2, n = t & 3;
        float a = bfc[n];
#pragma unroll
        for (int m = 0; m < 32; ++m) a = fmaf(x32[b][m], Wfc[m * 4 + n], a);
        px[b][n] = a;
    }
    __syncthreads();
    // emb = concat(pooled, plugx); write emb to dout[16:]
    for (int idx = t; idx < BS_ * 54; idx += 256) {
        int b = idx / 54, c = idx % 54;
        float v = (c < 50) ? pooled[b * 50 + c] : px[b][c - 50];
        embs[b][c] = v;
        dout[16 + idx] = v;
    }
    __syncthreads();
    // f1
    for (int idx = t; idx < 512; idx += 256) {
        int b = idx >> 5, c = idx & 31;
        float a = bf1[c];
#pragma unroll
        for (int k = 0; k < 54; ++k) a = fmaf(embs[b][k], Wf1[k * 32 + c], a);
        t1[b][c] = a;
    }
    __syncthreads();
    // f2
    {
        int b = t >> 4, c = t & 15;
        float a = bf2[c];
#pragma unroll
        for (int k = 0; k < 32; ++k) a = fmaf(t1[b][k], Wf2[k * 16 + c], a);
        t2[b][c] = a;
    }
    __syncthreads();
    // f3 -> out
    if (t < 16) {
        float a = bf3[0];
#pragma unroll
        for (int k = 0; k < 16; ++k) a = fmaf(t2[t][k], Wf3[k], a);
        dout[t] = a;
    }
}

// ---------------- launcher ----------------
extern "C" void kernel_launch(void* const* d_in, const int* in_sizes, int n_in,
                              void* d_out, int out_size, void* d_ws, size_t ws_size,
                              hipStream_t stream) {
    const float* x      = (const float*)d_in[0];
    const int*   ei     = (const int*)d_in[1];
    const float* gender = (const float*)d_in[2];
    const float* age    = (const float*)d_in[3];
    const float* handed = (const float*)d_in[4];
    const float* W1  = (const float*)d_in[5];
    const float* b1  = (const float*)d_in[6];
    const float* Wl2 = (const float*)d_in[7];
    const float* Wr2 = (const float*)d_in[8];
    const float* b2  = (const float*)d_in[9];
    const float* Wl3 = (const float*)d_in[10];
    const float* Wr3 = (const float*)d_in[11];
    const float* b3  = (const float*)d_in[12];
    const float* Wl4 = (const float*)d_in[13];
    const float* Wr4 = (const float*)d_in[14];
    const float* b4  = (const float*)d_in[15];
    const float* Wq  = (const float*)d_in[16];
    const float* bq  = (const float*)d_in[17];
    const float* Wk  = (const float*)d_in[18];
    const float* bk  = (const float*)d_in[19];
    const float* Wv  = (const float*)d_in[20];
    const float* bv  = (const float*)d_in[21];
    const float* Wfc = (const float*)d_in[22];
    const float* bfc = (const float*)d_in[23];
    const float* Wf1 = (const float*)d_in[24];
    const float* bf1 = (const float*)d_in[25];
    const float* Wf2 = (const float*)d_in[26];
    const float* bf2 = (const float*)d_in[27];
    const float* Wf3 = (const float*)d_in[28];
    const float* bf3 = (const float*)d_in[29];

    const int* srcp = ei;
    const int* dstp = ei + EE;

    char* wsb = (char*)d_ws;
    size_t off = 0;
    auto alloc = [&](size_t bytes) -> char* {
        char* p = wsb + off;
        off += (bytes + 255) & ~(size_t)255;
        return p;
    };
    float* A      = (float*)alloc((size_t)NN * 320 * 4);  // 84 MB
    float* B      = (float*)alloc((size_t)NN * 320 * 4);  // 84 MB
    float* C      = (float*)alloc((size_t)NN * 180 * 4);  // 47 MB
    int*   indeg  = (int*)alloc((size_t)NN * 4);
    int*   rowptr = (int*)alloc((size_t)(NN + 1) * 4);
    int*   cursor = (int*)alloc((size_t)(NN + 1) * 4);
    int*   csr    = (int*)alloc((size_t)EE * 4);
    float* dinv   = (float*)alloc((size_t)NN * 4);
    float* stats  = (float*)alloc(1024 * 4);
    float* pooled = (float*)alloc(16 * 64 * 4);
    float* dout   = (float*)d_out;

    // graph preprocessing
    hipMemsetAsync(indeg, 0, (size_t)NN * 4, stream);
    k_indeg<<<EE / 256, 256, 0, stream>>>(dstp, indeg);
    k_scan<<<1, 256, 0, stream>>>(indeg, rowptr, cursor);
    k_fill<<<EE / 256, 256, 0, stream>>>(srcp, dstp, cursor, csr);
    k_dinv<<<NN / 256, 256, 0, stream>>>(indeg, dinv);

    // layer 1: GCN
    k_gemm<false, false><<<dim3(NN / BM, 5), 256, 0, stream>>>(x, W1, nullptr, A, NN, 640, 320);
    k_gcn_agg<320><<<NN / 4, 256, 0, stream>>>(A, rowptr, csr, dinv, b1, B);
    hipMemsetAsync(stats, 0, 4096, stream);
    k_bn_stats<320><<<256, 256, 0, stream>>>(B, stats);
    k_bn_apply<320><<<2048, 256, 0, stream>>>(B, stats);

    // layer 2: SAGE 320->180
    k_sage_mean<320><<<NN / 4, 256, 0, stream>>>(B, rowptr, csr, indeg, A);
    k_gemm<false, true><<<dim3(NN / BM, 3), 256, 0, stream>>>(B, Wr2, b2, C, NN, 320, 180);
    k_gemm<true, false><<<dim3(NN / BM, 3), 256, 0, stream>>>(A, Wl2, nullptr, C, NN, 320, 180);
    hipMemsetAsync(stats, 0, 4096, stream);
    k_bn_stats<180><<<256, 256, 0, stream>>>(C, stats);
    k_bn_apply<180><<<2048, 256, 0, stream>>>(C, stats);

    // layer 3: SAGE 180->90
    k_sage_mean<180><<<NN / 4, 256, 0, stream>>>(C, rowptr, csr, indeg, A);
    k_gemm<false, true><<<dim3(NN / BM, 2), 256, 0, stream>>>(C, Wr3, b3, B, NN, 180, 90);
    k_gemm<true, false><<<dim3(NN / BM, 2), 256, 0, stream>>>(A, Wl3, nullptr, B, NN, 180, 90);
    hipMemsetAsync(stats, 0, 4096, stream);
    k_bn_stats<90><<<256, 256, 0, stream>>>(B, stats);
    k_bn_apply<90><<<2048, 256, 0, stream>>>(B, stats);

    // layer 4: SAGE 90->50
    k_sage_mean<90><<<NN / 4, 256, 0, stream>>>(B, rowptr, csr, indeg, A);
    k_gemm<false, true><<<dim3(NN / BM, 1), 256, 0, stream>>>(B, Wr4, b4, C, NN, 90, 50);
    k_gemm<true, false><<<dim3(NN / BM, 1), 256, 0, stream>>>(A, Wl4, nullptr, C, NN, 90, 50);
    hipMemsetAsync(stats, 0, 4096, stream);
    k_bn_stats<50><<<256, 256, 0, stream>>>(C, stats);
    k_bn_apply<50><<<2048, 256, 0, stream>>>(C, stats);

    // pooling + head
    k_pool<<<16, 256, 0, stream>>>(C, pooled);
    k_head<<<1, 256, 0, stream>>>(gender, age, handed, Wq, bq, Wk, bk, Wv, bv,
                                  Wfc, bfc, Wf1, bf1, Wf2, bf2, Wf3, bf3, pooled, dout);
}

// Round 2
// 1531.830 us; speedup vs baseline: 1.7256x; 1.7256x over previous
//
#include <hip/hip_runtime.h>
#include <cstdint>

#define NN 65536
#define EE 524288
#define BS_ 16

typedef unsigned short u16;
typedef unsigned int u32;
typedef __attribute__((ext_vector_type(8))) short short8v;
typedef __attribute__((ext_vector_type(4))) float f32x4;

// ---------------- bf16 split helpers ----------------
__device__ __forceinline__ u16 f2bf(float f) {
    u32 u = __float_as_uint(f);
    u32 r = (u + 0x7fffu + ((u >> 16) & 1u)) >> 16;
    return (u16)r;
}
__device__ __forceinline__ float bff(u16 h) {
    return __uint_as_float(((u32)h) << 16);
}

// ---------------- threefry2x32 (JAX-compatible, key = (0,42)) ----------------
__device__ __forceinline__ u32 rotl32(u32 x, int d) {
    return (x << d) | (x >> (32 - d));
}
__device__ __forceinline__ void threefry_0_42(u32& x0, u32& x1) {
    const u32 ks0 = 0u, ks1 = 42u, ks2 = 0u ^ 42u ^ 0x1BD11BDAu;
    x0 += ks0; x1 += ks1;
#define RND(r) { x0 += x1; x1 = rotl32(x1, r); x1 ^= x0; }
    RND(13) RND(15) RND(26) RND(6)  x0 += ks1; x1 += ks2 + 1u;
    RND(17) RND(29) RND(16) RND(24) x0 += ks2; x1 += ks0 + 2u;
    RND(13) RND(15) RND(26) RND(6)  x0 += ks0; x1 += ks1 + 3u;
    RND(17) RND(29) RND(16) RND(24) x0 += ks1; x1 += ks2 + 4u;
    RND(13) RND(15) RND(26) RND(6)  x0 += ks2; x1 += ks0 + 5u;
#undef RND
}

// ---------------- graph preprocessing ----------------
__global__ void k_indeg(const int* __restrict__ dst, int* __restrict__ indeg) {
    int e = blockIdx.x * 256 + threadIdx.x;
    if (e < EE) atomicAdd(&indeg[dst[e]], 1);
}

__global__ void k_scan(const int* __restrict__ indeg, int* __restrict__ rowptr,
                       int* __restrict__ cursor) {
    __shared__ int psum[256];
    int t = threadIdx.x;
    int base = t * 256;
    int s = 0;
    for (int i = 0; i < 256; ++i) s += indeg[base + i];
    psum[t] = s;
    __syncthreads();
    for (int off = 1; off < 256; off <<= 1) {
        int v = (t >= off) ? psum[t - off] : 0;
        __syncthreads();
        psum[t] += v;
        __syncthreads();
    }
    int run = (t == 0) ? 0 : psum[t - 1];
    for (int i = 0; i < 256; ++i) {
        rowptr[base + i] = run;
        cursor[base + i] = run;
        run += indeg[base + i];
    }
    if (t == 255) rowptr[NN] = run;
}

__global__ void k_fill(const int* __restrict__ src, const int* __restrict__ dst,
                       int* __restrict__ cursor, int* __restrict__ csr) {
    int e = blockIdx.x * 256 + threadIdx.x;
    if (e < EE) {
        int d = dst[e];
        int p = atomicAdd(&cursor[d], 1);
        csr[p] = src[e];
    }
}

__global__ void k_dinv(const int* __restrict__ indeg, float* __restrict__ dinv) {
    int i = blockIdx.x * 256 + threadIdx.x;
    if (i < NN) dinv[i] = rsqrtf((float)indeg[i] + 1.0f);
}

// ---------------- weight transpose + hi/lo bf16 split ----------------
// W[K][N] fp32 -> Wh/Wl [NPW][KP] bf16, zero-padded (n>=N or k>=K -> 0)
__global__ void k_wsplit(const float* __restrict__ W, int K, int N, int KP, int NPW,
                         u16* __restrict__ Wh, u16* __restrict__ Wl) {
    int idx = blockIdx.x * 256 + threadIdx.x;
    if (idx >= NPW * KP) return;
    int n = idx / KP, k = idx % KP;
    float v = (n < N && k < K) ? W[(size_t)k * N + n] : 0.f;
    u16 h = f2bf(v);
    u16 l = f2bf(v - bff(h));
    Wh[idx] = h;
    Wl[idx] = l;
}

// ---------------- split-bf16 MFMA GEMM ----------------
// C[M x CS] = A1[M x KP1] @ W1 + A2[M x KP2] @ W2 (+bias), M=65536
// Block: 64 rows x 128 cols, 4 waves (2x2), wave tile 32x64.
// W* are pre-transposed padded bf16 [NPW][KP] (hi/lo). A strides (lda) are
// multiples of 64 so staging needs no k-mask; W pads are zero so A pad
// garbage contributes 0.
template <bool BIAS>
__global__ __launch_bounds__(256, 2) void k_gemm_mfma(
    const float* __restrict__ A1, const u16* __restrict__ W1h, const u16* __restrict__ W1l,
    int KP1, int lda1,
    const float* __restrict__ A2, const u16* __restrict__ W2h, const u16* __restrict__ W2l,
    int KP2, int lda2,
    const float* __restrict__ bias, float* __restrict__ C, int N, int CS) {
    __shared__ u16 Ah[64][72];   // +8 pad: frag ds_read_b128 is 2-way (free)
    __shared__ u16 Al[64][72];
    __shared__ u16 Wh[128][72];
    __shared__ u16 Wl[128][72];

    const int t = threadIdx.x;
    const int bm = blockIdx.x * 64;
    const int bn = blockIdx.y * 128;
    const int lane = t & 63;
    const int wid = t >> 6;
    const int wr = wid >> 1, wc = wid & 1;

    f32x4 acc[2][4];
#pragma unroll
    for (int m = 0; m < 2; ++m)
#pragma unroll
        for (int n = 0; n < 4; ++n) acc[m][n] = (f32x4){0.f, 0.f, 0.f, 0.f};

    const int sr = t >> 4;          // 0..15
    const int sc4 = (t & 15) * 4;   // 0..60

    for (int ph = 0; ph < 2; ++ph) {
        const float* A = ph ? A2 : A1;
        if (A == nullptr) continue;
        const u16* Wgh = ph ? W2h : W1h;
        const u16* Wgl = ph ? W2l : W1l;
        const int KP = ph ? KP2 : KP1;
        const int lda = ph ? lda2 : lda1;
        for (int k0 = 0; k0 < KP; k0 += 64) {
            // stage A (fp32 -> hi/lo bf16)
#pragma unroll
            for (int p = 0; p < 4; ++p) {
                int rr = sr + 16 * p;
                const float4 v = *(const float4*)(A + (size_t)(bm + rr) * lda + k0 + sc4);
                u16 h0 = f2bf(v.x), h1 = f2bf(v.y), h2 = f2bf(v.z), h3 = f2bf(v.w);
                u16 l0 = f2bf(v.x - bff(h0)), l1 = f2bf(v.y - bff(h1));
                u16 l2 = f2bf(v.z - bff(h2)), l3 = f2bf(v.w - bff(h3));
                uint2 hh, ll;
                hh.x = (u32)h0 | ((u32)h1 << 16); hh.y = (u32)h2 | ((u32)h3 << 16);
                ll.x = (u32)l0 | ((u32)l1 << 16); ll.y = (u32)l2 | ((u32)l3 << 16);
                *(uint2*)&Ah[rr][sc4] = hh;
                *(uint2*)&Al[rr][sc4] = ll;
            }
            // stage W (bf16 copy)
#pragma unroll
            for (int p = 0; p < 8; ++p) {
                int nn = sr + 16 * p;
                size_t go = (size_t)(bn + nn) * KP + k0 + sc4;
                *(uint2*)&Wh[nn][sc4] = *(const uint2*)(Wgh + go);
                *(uint2*)&Wl[nn][sc4] = *(const uint2*)(Wgl + go);
            }
            __syncthreads();
            const int fr = lane & 15;
            const int kg = (lane >> 4) * 8;
#pragma unroll
            for (int kk = 0; kk < 64; kk += 32) {
                short8v a_h[2], a_l[2], w_h[4], w_l[4];
#pragma unroll
                for (int m = 0; m < 2; ++m) {
                    a_h[m] = *(const short8v*)&Ah[wr * 32 + m * 16 + fr][kk + kg];
                    a_l[m] = *(const short8v*)&Al[wr * 32 + m * 16 + fr][kk + kg];
                }
#pragma unroll
                for (int n = 0; n < 4; ++n) {
                    w_h[n] = *(const short8v*)&Wh[wc * 64 + n * 16 + fr][kk + kg];
                    w_l[n] = *(const short8v*)&Wl[wc * 64 + n * 16 + fr][kk + kg];
                }
#pragma unroll
                for (int m = 0; m < 2; ++m)
#pragma unroll
                    for (int n = 0; n < 4; ++n) {
                        acc[m][n] = __builtin_amdgcn_mfma_f32_16x16x32_bf16(a_h[m], w_h[n], acc[m][n], 0, 0, 0);
                        acc[m][n] = __builtin_amdgcn_mfma_f32_16x16x32_bf16(a_h[m], w_l[n], acc[m][n], 0, 0, 0);
                        acc[m][n] = __builtin_amdgcn_mfma_f32_16x16x32_bf16(a_l[m], w_h[n], acc[m][n], 0, 0, 0);
                    }
            }
            __syncthreads();
        }
    }
    // epilogue: C/D frag col = lane&15, row = (lane>>4)*4 + reg
    const int fr = lane & 15, fq = lane >> 4;
#pragma unroll
    for (int m = 0; m < 2; ++m) {
        int row = bm + wr * 32 + m * 16 + fq * 4;
#pragma unroll
        for (int n = 0; n < 4; ++n) {
            int col = bn + wc * 64 + n * 16 + fr;
            if (col < CS) {
                float b = (BIAS && col < N) ? bias[col] : 0.f;
#pragma unroll
                for (int e = 0; e < 4; ++e)
                    C[(size_t)(row + e) * CS + col] = acc[m][n][e] + b;
            }
        }
    }
}

// ---------------- GCN aggregation, D=320 (float4) ----------------
__global__ __launch_bounds__(256) void k_gcn_agg320(const float* __restrict__ h,
                                                    const int* __restrict__ rowptr,
                                                    const int* __restrict__ csr,
                                                    const float* __restrict__ dinv,
                                                    const float* __restrict__ bias,
                                                    float* __restrict__ out) {
    int lane = threadIdx.x & 63;
    int n = blockIdx.x * 4 + (threadIdx.x >> 6);
    bool has1 = lane < 16;
    float di = dinv[n];
    float s2 = di * di;
    const float4* hn = (const float4*)(h + (size_t)n * 320);
    float4 v0 = hn[lane];
    float4 a0 = make_float4(v0.x * s2, v0.y * s2, v0.z * s2, v0.w * s2);
    float4 a1 = make_float4(0.f, 0.f, 0.f, 0.f);
    if (has1) {
        float4 v1 = hn[64 + lane];
        a1 = make_float4(v1.x * s2, v1.y * s2, v1.z * s2, v1.w * s2);
    }
    int e1 = rowptr[n + 1];
    for (int e = rowptr[n]; e < e1; ++e) {
        int s = csr[e];
        float w = dinv[s] * di;
        const float4* hs = (const float4*)(h + (size_t)s * 320);
        float4 u0 = hs[lane];
        a0.x = fmaf(u0.x, w, a0.x); a0.y = fmaf(u0.y, w, a0.y);
        a0.z = fmaf(u0.z, w, a0.z); a0.w = fmaf(u0.w, w, a0.w);
        if (has1) {
            float4 u1 = hs[64 + lane];
            a1.x = fmaf(u1.x, w, a1.x); a1.y = fmaf(u1.y, w, a1.y);
            a1.z = fmaf(u1.z, w, a1.z); a1.w = fmaf(u1.w, w, a1.w);
        }
    }
    const float4* b4 = (const float4*)bias;
    float4* on = (float4*)(out + (size_t)n * 320);
    float4 bb = b4[lane];
    on[lane] = make_float4(a0.x + bb.x, a0.y + bb.y, a0.z + bb.z, a0.w + bb.w);
    if (has1) {
        float4 bb1 = b4[64 + lane];
        on[64 + lane] = make_float4(a1.x + bb1.x, a1.y + bb1.y, a1.z + bb1.z, a1.w + bb1.w);
    }
}

// ---------------- SAGE mean aggregation (float4), CH chunks of 4 ----------------
template <int STR, int CH>
__global__ __launch_bounds__(256) void k_sage4(const float* __restrict__ x,
                                               const int* __restrict__ rowptr,
                                               const int* __restrict__ csr,
                                               const int* __restrict__ indeg,
                                               float* __restrict__ mean) {
    constexpr int NI = (CH + 63) / 64;
    int lane = threadIdx.x & 63;
    int n = blockIdx.x * 4 + (threadIdx.x >> 6);
    float4 acc[NI];
#pragma unroll
    for (int j = 0; j < NI; ++j) acc[j] = make_float4(0.f, 0.f, 0.f, 0.f);
    int e1 = rowptr[n + 1];
    for (int e = rowptr[n]; e < e1; ++e) {
        int s = csr[e];
        const float4* xs = (const float4*)(x + (size_t)s * STR);
#pragma unroll
        for (int j = 0; j < NI; ++j) {
            int ch = lane + 64 * j;
            if (ch < CH) {
                float4 u = xs[ch];
                acc[j].x += u.x; acc[j].y += u.y; acc[j].z += u.z; acc[j].w += u.w;
            }
        }
    }
    int cnt = indeg[n];
    float inv = 1.0f / (float)(cnt > 1 ? cnt : 1);
    float4* mn = (float4*)(mean + (size_t)n * STR);
#pragma unroll
    for (int j = 0; j < NI; ++j) {
        int ch = lane + 64 * j;
        if (ch < CH)
            mn[ch] = make_float4(acc[j].x * inv, acc[j].y * inv, acc[j].z * inv, acc[j].w * inv);
    }
}

// float2 variant (for D=90, stride 128)
template <int STR, int CH>
__global__ __launch_bounds__(256) void k_sage2(const float* __restrict__ x,
                                               const int* __restrict__ rowptr,
                                               const int* __restrict__ csr,
                                               const int* __restrict__ indeg,
                                               float* __restrict__ mean) {
    int lane = threadIdx.x & 63;
    int n = blockIdx.x * 4 + (threadIdx.x >> 6);
    float2 acc = make_float2(0.f, 0.f);
    bool act = lane < CH;
    int e1 = rowptr[n + 1];
    for (int e = rowptr[n]; e < e1; ++e) {
        int s = csr[e];
        if (act) {
            float2 u = ((const float2*)(x + (size_t)s * STR))[lane];
            acc.x += u.x; acc.y += u.y;
        }
    }
    int cnt = indeg[n];
    float inv = 1.0f / (float)(cnt > 1 ? cnt : 1);
    if (act)
        ((float2*)(mean + (size_t)n * STR))[lane] = make_float2(acc.x * inv, acc.y * inv);
}

// ---------------- batchnorm (leaky_relu fused) ----------------
template <int D, int STR>
__global__ __launch_bounds__(256) void k_bn_stats(const float* __restrict__ x,
                                                  float* __restrict__ stats) {
    constexpr int NC = (D + 255) / 256;
    int t = threadIdx.x;
    int r0 = blockIdx.x * 256;
    float s[NC], q[NC];
#pragma unroll
    for (int i = 0; i < NC; ++i) { s[i] = 0.f; q[i] = 0.f; }
    for (int r = r0; r < r0 + 256; ++r) {
        const float* row = x + (size_t)r * STR;
#pragma unroll
        for (int i = 0; i < NC; ++i) {
            int c = t + 256 * i;
            if (c < D) {
                float v = row[c];
                v = v >= 0.f ? v : 0.01f * v;
                s[i] += v;
                q[i] += v * v;
            }
        }
    }
#pragma unroll
    for (int i = 0; i < NC; ++i) {
        int c = t + 256 * i;
        if (c < D) {
            atomicAdd(&stats[c], s[i]);
            atomicAdd(&stats[512 + c], q[i]);
        }
    }
}

template <int STR>
__global__ __launch_bounds__(256) void k_bn_apply(float* __restrict__ x,
                                                  const float* __restrict__ stats) {
    const float invN = 1.0f / (float)NN;
    size_t total4 = (size_t)NN * STR / 4;
    size_t stride = (size_t)gridDim.x * 256;
    for (size_t i = (size_t)blockIdx.x * 256 + threadIdx.x; i < total4; i += stride) {
        int c = (int)((i * 4) % STR);
        float4 v = ((const float4*)x)[i];
        float4 m4 = *(const float4*)(stats + c);
        float4 q4 = *(const float4*)(stats + 512 + c);
        float4 o;
        {
            float mu = m4.x * invN, var = q4.x * invN - mu * mu;
            float u = v.x >= 0.f ? v.x : 0.01f * v.x;
            o.x = (u - mu) * rsqrtf(var + 1e-5f);
        }
        {
            float mu = m4.y * invN, var = q4.y * invN - mu * mu;
            float u = v.y >= 0.f ? v.y : 0.01f * v.y;
            o.y = (u - mu) * rsqrtf(var + 1e-5f);
        }
        {
            float mu = m4.z * invN, var = q4.z * invN - mu * mu;
            float u = v.z >= 0.f ? v.z : 0.01f * v.z;
            o.z = (u - mu) * rsqrtf(var + 1e-5f);
        }
        {
            float mu = m4.w * invN, var = q4.w * invN - mu * mu;
            float u = v.w >= 0.f ? v.w : 0.01f * v.w;
            o.w = (u - mu) * rsqrtf(var + 1e-5f);
        }
        ((float4*)x)[i] = o;
    }
}

// ---------------- pooling (input stride 64) ----------------
__global__ __launch_bounds__(256) void k_pool(const float* __restrict__ h,
                                              float* __restrict__ pooled) {
    int blk = blockIdx.x;  // 256 blocks: 16 batches x 16 segments
    int batch = blk >> 4, seg = blk & 15;
    int f = threadIdx.x & 63, g = threadIdx.x >> 6;
    size_t base = ((size_t)batch * 4096 + seg * 256 + g) * 64 + f;
    float acc = 0.f;
    for (int i = 0; i < 64; ++i) acc += h[base + (size_t)i * 256];
    atomicAdd(&pooled[batch * 64 + f], acc);
}

// ---------------- head: attention plug + final MLP (pooled stride 64) ----------------
__global__ __launch_bounds__(256) void k_head(
    const float* __restrict__ gender, const float* __restrict__ age,
    const float* __restrict__ handed, const float* __restrict__ Wq,
    const float* __restrict__ bq, const float* __restrict__ Wk,
    const float* __restrict__ bk, const float* __restrict__ Wv,
    const float* __restrict__ bv, const float* __restrict__ Wfc,
    const float* __restrict__ bfc, const float* __restrict__ Wf1,
    const float* __restrict__ bf1, const float* __restrict__ Wf2,
    const float* __restrict__ bf2, const float* __restrict__ Wf3,
    const float* __restrict__ bf3, const float* __restrict__ pooled,
    float* __restrict__ dout) {
    __shared__ float plug[BS_][8];
    __shared__ float qs[BS_][32], ks[BS_][32], vs[BS_][32];
    __shared__ float gum[256];
    __shared__ float x32[BS_][32];
    __shared__ float px[BS_][4];
    __shared__ float embs[BS_][54];
    __shared__ float t1[BS_][32];
    __shared__ float t2[BS_][16];
    int t = threadIdx.x;

    if (t < 128) {
        int b = t >> 3, c = t & 7;
        float v;
        if (c < 2) v = gender[b * 2 + c];
        else if (c == 2) v = age[b];
        else v = handed[b * 5 + (c - 3)];
        plug[b][c] = v;
    }
    {
        u32 lane = (u32)(t & 127);
        u32 a = lane, b2 = lane + 128u;
        threefry_0_42(a, b2);
        u32 bits = (t < 128) ? a : b2;
        float u = __uint_as_float((bits >> 9) | 0x3f800000u) - 1.0f;
        const float mn = 1e-9f;
        u = u * (1.0f - mn) + mn;
        u = fmaxf(mn, u);
        gum[t] = -logf(-logf(u));
    }
    __syncthreads();
    for (int idx = t; idx < 512; idx += 256) {
        int b = idx >> 5, c = idx & 31;
        float aq = bq[c], ak = bk[c], av = bv[c];
#pragma unroll
        for (int i = 0; i < 8; ++i) {
            float p = plug[b][i];
            aq = fmaf(p, Wq[i * 32 + c], aq);
            ak = fmaf(p, Wk[i * 32 + c], ak);
            av = fmaf(p, Wv[i * 32 + c], av);
        }
        qs[b][c] = aq; ks[b][c] = ak; vs[b][c] = av;
    }
    __syncthreads();
    if (t < 64) {
        int b = t >> 2, h = t & 3;
        const float isq = 0.35355339059327373f;
        const float sq = 2.8284271247461903f;
        float sc[4];
#pragma unroll
        for (int j = 0; j < 4; ++j) {
            float d = 0.f;
#pragma unroll
            for (int dd = 0; dd < 8; ++dd) d = fmaf(qs[b][h * 8 + dd], ks[b][j * 8 + dd], d);
            sc[j] = d * isq + gum[b * 16 + h * 4 + j];
        }
        float m = fmaxf(fmaxf(sc[0], sc[1]), fmaxf(sc[2], sc[3]));
        float e0 = expf(sc[0] - m), e1 = expf(sc[1] - m), e2 = expf(sc[2] - m), e3 = expf(sc[3] - m);
        float sum = e0 + e1 + e2 + e3;
        float a0 = e0 / sum * sq, a1 = e1 / sum * sq, a2 = e2 / sum * sq, a3 = e3 / sum * sq;
#pragma unroll
        for (int dd = 0; dd < 8; ++dd) {
            float o = a0 * vs[b][0 * 8 + dd] + a1 * vs[b][1 * 8 + dd] +
                      a2 * vs[b][2 * 8 + dd] + a3 * vs[b][3 * 8 + dd];
            x32[b][h * 8 + dd] = o;
        }
    }
    __syncthreads();
    if (t < 64) {
        int b = t >> 2, n = t & 3;
        float a = bfc[n];
#pragma unroll
        for (int m = 0; m < 32; ++m) a = fmaf(x32[b][m], Wfc[m * 4 + n], a);
        px[b][n] = a;
    }
    __syncthreads();
    for (int idx = t; idx < BS_ * 54; idx += 256) {
        int b = idx / 54, c = idx % 54;
        float v = (c < 50) ? pooled[b * 64 + c] : px[b][c - 50];
        embs[b][c] = v;
        dout[16 + idx] = v;
    }
    __syncthreads();
    for (int idx = t; idx < 512; idx += 256) {
        int b = idx >> 5, c = idx & 31;
        float a = bf1[c];
#pragma unroll
        for (int k = 0; k < 54; ++k) a = fmaf(embs[b][k], Wf1[k * 32 + c], a);
        t1[b][c] = a;
    }
    __syncthreads();
    {
        int b = t >> 4, c = t & 15;
        float a = bf2[c];
#pragma unroll
        for (int k = 0; k < 32; ++k) a = fmaf(t1[b][k], Wf2[k * 16 + c], a);
        t2[b][c] = a;
    }
    __syncthreads();
    if (t < 16) {
        float a = bf3[0];
#pragma unroll
        for (int k = 0; k < 16; ++k) a = fmaf(t2[t][k], Wf3[k], a);
        dout[t] = a;
    }
}

// ---------------- launcher ----------------
extern "C" void kernel_launch(void* const* d_in, const int* in_sizes, int n_in,
                              void* d_out, int out_size, void* d_ws, size_t ws_size,
                              hipStream_t stream) {
    const float* x      = (const float*)d_in[0];
    const int*   ei     = (const int*)d_in[1];
    const float* gender = (const float*)d_in[2];
    const float* age    = (const float*)d_in[3];
    const float* handed = (const float*)d_in[4];
    const float* W1  = (const float*)d_in[5];
    const float* b1  = (const float*)d_in[6];
    const float* Wl2 = (const float*)d_in[7];
    const float* Wr2 = (const float*)d_in[8];
    const float* b2  = (const float*)d_in[9];
    const float* Wl3 = (const float*)d_in[10];
    const float* Wr3 = (const float*)d_in[11];
    const float* b3  = (const float*)d_in[12];
    const float* Wl4 = (const float*)d_in[13];
    const float* Wr4 = (const float*)d_in[14];
    const float* b4  = (const float*)d_in[15];
    const float* Wq  = (const float*)d_in[16];
    const float* bq  = (const float*)d_in[17];
    const float* Wk  = (const float*)d_in[18];
    const float* bk  = (const float*)d_in[19];
    const float* Wv  = (const float*)d_in[20];
    const float* bv  = (const float*)d_in[21];
    const float* Wfc = (const float*)d_in[22];
    const float* bfc = (const float*)d_in[23];
    const float* Wf1 = (const float*)d_in[24];
    const float* bf1 = (const float*)d_in[25];
    const float* Wf2 = (const float*)d_in[26];
    const float* bf2 = (const float*)d_in[27];
    const float* Wf3 = (const float*)d_in[28];
    const float* bf3 = (const float*)d_in[29];

    const int* srcp = ei;
    const int* dstp = ei + EE;

    char* wsb = (char*)d_ws;
    size_t off = 0;
    auto alloc = [&](size_t bytes) -> char* {
        char* p = wsb + off;
        off += (bytes + 255) & ~(size_t)255;
        return p;
    };
    float* P = (float*)alloc((size_t)NN * 320 * 4);
    float* Q = (float*)alloc((size_t)NN * 320 * 4);
    float* R = (float*)alloc((size_t)NN * 192 * 4);
    int* indeg  = (int*)alloc((size_t)NN * 4);
    int* rowptr = (int*)alloc((size_t)(NN + 1) * 4);
    int* cursor = (int*)alloc((size_t)(NN + 1) * 4);
    int* csr    = (int*)alloc((size_t)EE * 4);
    float* dinv = (float*)alloc((size_t)NN * 4);
    float* stats  = (float*)alloc(1024 * 4);
    float* pooled = (float*)alloc(16 * 64 * 4);
    // weight splits: [NPW][KP] bf16 hi/lo
    u16* W1th  = (u16*)alloc((size_t)384 * 640 * 2);
    u16* W1tl  = (u16*)alloc((size_t)384 * 640 * 2);
    u16* Wr2th = (u16*)alloc((size_t)256 * 320 * 2);
    u16* Wr2tl = (u16*)alloc((size_t)256 * 320 * 2);
    u16* Wl2th = (u16*)alloc((size_t)256 * 320 * 2);
    u16* Wl2tl = (u16*)alloc((size_t)256 * 320 * 2);
    u16* Wr3th = (u16*)alloc((size_t)128 * 192 * 2);
    u16* Wr3tl = (u16*)alloc((size_t)128 * 192 * 2);
    u16* Wl3th = (u16*)alloc((size_t)128 * 192 * 2);
    u16* Wl3tl = (u16*)alloc((size_t)128 * 192 * 2);
    u16* Wr4th = (u16*)alloc((size_t)128 * 128 * 2);
    u16* Wr4tl = (u16*)alloc((size_t)128 * 128 * 2);
    u16* Wl4th = (u16*)alloc((size_t)128 * 128 * 2);
    u16* Wl4tl = (u16*)alloc((size_t)128 * 128 * 2);
    float* dout = (float*)d_out;

    // graph preprocessing
    hipMemsetAsync(indeg, 0, (size_t)NN * 4, stream);
    k_indeg<<<EE / 256, 256, 0, stream>>>(dstp, indeg);
    k_scan<<<1, 256, 0, stream>>>(indeg, rowptr, cursor);
    k_fill<<<EE / 256, 256, 0, stream>>>(srcp, dstp, cursor, csr);
    k_dinv<<<NN / 256, 256, 0, stream>>>(indeg, dinv);

    // weight splits
    k_wsplit<<<(384 * 640 + 255) / 256, 256, 0, stream>>>(W1, 640, 320, 640, 384, W1th, W1tl);
    k_wsplit<<<(256 * 320 + 255) / 256, 256, 0, stream>>>(Wr2, 320, 180, 320, 256, Wr2th, Wr2tl);
    k_wsplit<<<(256 * 320 + 255) / 256, 256, 0, stream>>>(Wl2, 320, 180, 320, 256, Wl2th, Wl2tl);
    k_wsplit<<<(128 * 192 + 255) / 256, 256, 0, stream>>>(Wr3, 180, 90, 192, 128, Wr3th, Wr3tl);
    k_wsplit<<<(128 * 192 + 255) / 256, 256, 0, stream>>>(Wl3, 180, 90, 192, 128, Wl3th, Wl3tl);
    k_wsplit<<<(128 * 128 + 255) / 256, 256, 0, stream>>>(Wr4, 90, 50, 128, 128, Wr4th, Wr4tl);
    k_wsplit<<<(128 * 128 + 255) / 256, 256, 0, stream>>>(Wl4, 90, 50, 128, 128, Wl4th, Wl4tl);

    // layer 1: GCN (640 -> 320)
    k_gemm_mfma<false><<<dim3(1024, 3), 256, 0, stream>>>(
        x, W1th, W1tl, 640, 640, nullptr, nullptr, nullptr, 0, 0, nullptr, P, 320, 320);
    k_gcn_agg320<<<NN / 4, 256, 0, stream>>>(P, rowptr, csr, dinv, b1, Q);
    hipMemsetAsync(stats, 0, 4096, stream);
    k_bn_stats<320, 320><<<256, 256, 0, stream>>>(Q, stats);
    k_bn_apply<320><<<2048, 256, 0, stream>>>(Q, stats);

    // layer 2: SAGE (320 -> 180, stride 192)
    k_sage4<320, 80><<<NN / 4, 256, 0, stream>>>(Q, rowptr, csr, indeg, P);
    k_gemm_mfma<true><<<dim3(1024, 2), 256, 0, stream>>>(
        Q, Wr2th, Wr2tl, 320, 320, P, Wl2th, Wl2tl, 320, 320, b2, R, 180, 192);
    hipMemsetAsync(stats, 0, 4096, stream);
    k_bn_stats<180, 192><<<256, 256, 0, stream>>>(R, stats);
    k_bn_apply<192><<<2048, 256, 0, stream>>>(R, stats);

    // layer 3: SAGE (180 -> 90, stride 128)
    k_sage4<192, 45><<<NN / 4, 256, 0, stream>>>(R, rowptr, csr, indeg, Q);
    k_gemm_mfma<true><<<dim3(1024, 1), 256, 0, stream>>>(
        R, Wr3th, Wr3tl, 192, 192, Q, Wl3th, Wl3tl, 192, 192, b3, P, 90, 128);
    hipMemsetAsync(stats, 0, 4096, stream);
    k_bn_stats<90, 128><<<256, 256, 0, stream>>>(P, stats);
    k_bn_apply<128><<<2048, 256, 0, stream>>>(P, stats);

    // layer 4: SAGE (90 -> 50, stride 64)
    k_sage2<128, 45><<<NN / 4, 256, 0, stream>>>(P, rowptr, csr, indeg, R);
    k_gemm_mfma<true><<<dim3(1024, 1), 256, 0, stream>>>(
        P, Wr4th, Wr4tl, 128, 128, R, Wl4th, Wl4tl, 128, 128, b4, Q, 50, 64);
    hipMemsetAsync(stats, 0, 4096, stream);
    k_bn_stats<50, 64><<<256, 256, 0, stream>>>(Q, stats);
    k_bn_apply<64><<<2048, 256, 0, stream>>>(Q, stats);

    // pooling + head
    hipMemsetAsync(pooled, 0, 16 * 64 * 4, stream);
    k_pool<<<256, 256, 0, stream>>>(Q, pooled);
    k_head<<<1, 256, 0, stream>>>(gender, age, handed, Wq, bq, Wk, bk, Wv, bv,
                                  Wfc, bfc, Wf1, bf1, Wf2, bf2, Wf3, bf3, pooled, dout);
}

// Round 4
// 1319.019 us; speedup vs baseline: 2.0040x; 1.1613x over previous
//
#include <hip/hip_runtime.h>
#include <cstdint>

#define NN 65536
#define EE 524288
#define BS_ 16

typedef unsigned short u16;
typedef unsigned int u32;
typedef __attribute__((ext_vector_type(8))) short short8v;
typedef __attribute__((ext_vector_type(4))) float f32x4;

// ---------------- bf16 split helpers ----------------
__device__ __forceinline__ u16 f2bf(float f) {
    u32 u = __float_as_uint(f);
    u32 r = (u + 0x7fffu + ((u >> 16) & 1u)) >> 16;
    return (u16)r;
}
__device__ __forceinline__ float bff(u16 h) {
    return __uint_as_float(((u32)h) << 16);
}

// ---------------- threefry2x32 (JAX-compatible, key = (0,42)) ----------------
__device__ __forceinline__ u32 rotl32(u32 x, int d) {
    return (x << d) | (x >> (32 - d));
}
__device__ __forceinline__ void threefry_0_42(u32& x0, u32& x1) {
    const u32 ks0 = 0u, ks1 = 42u, ks2 = 0u ^ 42u ^ 0x1BD11BDAu;
    x0 += ks0; x1 += ks1;
#define RND(r) { x0 += x1; x1 = rotl32(x1, r); x1 ^= x0; }
    RND(13) RND(15) RND(26) RND(6)  x0 += ks1; x1 += ks2 + 1u;
    RND(17) RND(29) RND(16) RND(24) x0 += ks2; x1 += ks0 + 2u;
    RND(13) RND(15) RND(26) RND(6)  x0 += ks0; x1 += ks1 + 3u;
    RND(17) RND(29) RND(16) RND(24) x0 += ks1; x1 += ks2 + 4u;
    RND(13) RND(15) RND(26) RND(6)  x0 += ks2; x1 += ks0 + 5u;
#undef RND
}

// ---------------- graph preprocessing ----------------
__global__ void k_indeg(const int* __restrict__ dst, int* __restrict__ indeg) {
    int e = blockIdx.x * 256 + threadIdx.x;
    if (e < EE) atomicAdd(&indeg[dst[e]], 1);
}

__global__ void k_scan(const int* __restrict__ indeg, int* __restrict__ rowptr,
                       int* __restrict__ cursor) {
    __shared__ int psum[256];
    int t = threadIdx.x;
    int base = t * 256;
    int s = 0;
    for (int i = 0; i < 256; ++i) s += indeg[base + i];
    psum[t] = s;
    __syncthreads();
    for (int off = 1; off < 256; off <<= 1) {
        int v = (t >= off) ? psum[t - off] : 0;
        __syncthreads();
        psum[t] += v;
        __syncthreads();
    }
    int run = (t == 0) ? 0 : psum[t - 1];
    for (int i = 0; i < 256; ++i) {
        rowptr[base + i] = run;
        cursor[base + i] = run;
        run += indeg[base + i];
    }
    if (t == 255) rowptr[NN] = run;
}

__global__ void k_fill(const int* __restrict__ src, const int* __restrict__ dst,
                       int* __restrict__ cursor, int* __restrict__ csr) {
    int e = blockIdx.x * 256 + threadIdx.x;
    if (e < EE) {
        int d = dst[e];
        int p = atomicAdd(&cursor[d], 1);
        csr[p] = src[e];
    }
}

__global__ void k_dinv(const int* __restrict__ indeg, float* __restrict__ dinv) {
    int i = blockIdx.x * 256 + threadIdx.x;
    if (i < NN) dinv[i] = rsqrtf((float)indeg[i] + 1.0f);
}

// ---------------- weight transpose + hi/lo bf16 split ----------------
__global__ void k_wsplit(const float* __restrict__ W, int K, int N, int KP, int NPW,
                         u16* __restrict__ Wh, u16* __restrict__ Wl) {
    int idx = blockIdx.x * 256 + threadIdx.x;
    if (idx >= NPW * KP) return;
    int n = idx / KP, k = idx % KP;
    float v = (n < N && k < K) ? W[(size_t)k * N + n] : 0.f;
    u16 h = f2bf(v);
    u16 l = f2bf(v - bff(h));
    Wh[idx] = h;
    Wl[idx] = l;
}

// ---------------- split-bf16 MFMA GEMM ----------------
template <bool BIAS>
__global__ __launch_bounds__(256, 2) void k_gemm_mfma(
    const float* __restrict__ A1, const u16* __restrict__ W1h, const u16* __restrict__ W1l,
    int KP1, int lda1,
    const float* __restrict__ A2, const u16* __restrict__ W2h, const u16* __restrict__ W2l,
    int KP2, int lda2,
    const float* __restrict__ bias, float* __restrict__ C, int N, int CS) {
    __shared__ u16 Ah[64][72];
    __shared__ u16 Al[64][72];
    __shared__ u16 Wh[128][72];
    __shared__ u16 Wl[128][72];

    const int t = threadIdx.x;
    const int bm = blockIdx.x * 64;
    const int bn = blockIdx.y * 128;
    const int lane = t & 63;
    const int wid = t >> 6;
    const int wr = wid >> 1, wc = wid & 1;

    f32x4 acc[2][4];
#pragma unroll
    for (int m = 0; m < 2; ++m)
#pragma unroll
        for (int n = 0; n < 4; ++n) acc[m][n] = (f32x4){0.f, 0.f, 0.f, 0.f};

    const int sr = t >> 4;
    const int sc4 = (t & 15) * 4;

    for (int ph = 0; ph < 2; ++ph) {
        const float* A = ph ? A2 : A1;
        if (A == nullptr) continue;
        const u16* Wgh = ph ? W2h : W1h;
        const u16* Wgl = ph ? W2l : W1l;
        const int KP = ph ? KP2 : KP1;
        const int lda = ph ? lda2 : lda1;
        for (int k0 = 0; k0 < KP; k0 += 64) {
#pragma unroll
            for (int p = 0; p < 4; ++p) {
                int rr = sr + 16 * p;
                const float4 v = *(const float4*)(A + (size_t)(bm + rr) * lda + k0 + sc4);
                u16 h0 = f2bf(v.x), h1 = f2bf(v.y), h2 = f2bf(v.z), h3 = f2bf(v.w);
                u16 l0 = f2bf(v.x - bff(h0)), l1 = f2bf(v.y - bff(h1));
                u16 l2 = f2bf(v.z - bff(h2)), l3 = f2bf(v.w - bff(h3));
                uint2 hh, ll;
                hh.x = (u32)h0 | ((u32)h1 << 16); hh.y = (u32)h2 | ((u32)h3 << 16);
                ll.x = (u32)l0 | ((u32)l1 << 16); ll.y = (u32)l2 | ((u32)l3 << 16);
                *(uint2*)&Ah[rr][sc4] = hh;
                *(uint2*)&Al[rr][sc4] = ll;
            }
#pragma unroll
            for (int p = 0; p < 8; ++p) {
                int nn = sr + 16 * p;
                size_t go = (size_t)(bn + nn) * KP + k0 + sc4;
                *(uint2*)&Wh[nn][sc4] = *(const uint2*)(Wgh + go);
                *(uint2*)&Wl[nn][sc4] = *(const uint2*)(Wgl + go);
            }
            __syncthreads();
            const int fr = lane & 15;
            const int kg = (lane >> 4) * 8;
#pragma unroll
            for (int kk = 0; kk < 64; kk += 32) {
                short8v a_h[2], a_l[2], w_h[4], w_l[4];
#pragma unroll
                for (int m = 0; m < 2; ++m) {
                    a_h[m] = *(const short8v*)&Ah[wr * 32 + m * 16 + fr][kk + kg];
                    a_l[m] = *(const short8v*)&Al[wr * 32 + m * 16 + fr][kk + kg];
                }
#pragma unroll
                for (int n = 0; n < 4; ++n) {
                    w_h[n] = *(const short8v*)&Wh[wc * 64 + n * 16 + fr][kk + kg];
                    w_l[n] = *(const short8v*)&Wl[wc * 64 + n * 16 + fr][kk + kg];
                }
#pragma unroll
                for (int m = 0; m < 2; ++m)
#pragma unroll
                    for (int n = 0; n < 4; ++n) {
                        acc[m][n] = __builtin_amdgcn_mfma_f32_16x16x32_bf16(a_h[m], w_h[n], acc[m][n], 0, 0, 0);
                        acc[m][n] = __builtin_amdgcn_mfma_f32_16x16x32_bf16(a_h[m], w_l[n], acc[m][n], 0, 0, 0);
                        acc[m][n] = __builtin_amdgcn_mfma_f32_16x16x32_bf16(a_l[m], w_h[n], acc[m][n], 0, 0, 0);
                    }
            }
            __syncthreads();
        }
    }
    const int fr = lane & 15, fq = lane >> 4;
#pragma unroll
    for (int m = 0; m < 2; ++m) {
        int row = bm + wr * 32 + m * 16 + fq * 4;
#pragma unroll
        for (int n = 0; n < 4; ++n) {
            int col = bn + wc * 64 + n * 16 + fr;
            if (col < CS) {
                float b = (BIAS && col < N) ? bias[col] : 0.f;
#pragma unroll
                for (int e = 0; e < 4; ++e)
                    C[(size_t)(row + e) * CS + col] = acc[m][n][e] + b;
            }
        }
    }
}

// ---------------- GCN aggregation, D=320 (float4) ----------------
__global__ __launch_bounds__(256) void k_gcn_agg320(const float* __restrict__ h,
                                                    const int* __restrict__ rowptr,
                                                    const int* __restrict__ csr,
                                                    const float* __restrict__ dinv,
                                                    const float* __restrict__ bias,
                                                    float* __restrict__ out) {
    int lane = threadIdx.x & 63;
    int n = blockIdx.x * 4 + (threadIdx.x >> 6);
    bool has1 = lane < 16;
    float di = dinv[n];
    float s2 = di * di;
    const float4* hn = (const float4*)(h + (size_t)n * 320);
    float4 v0 = hn[lane];
    float4 a0 = make_float4(v0.x * s2, v0.y * s2, v0.z * s2, v0.w * s2);
    float4 a1 = make_float4(0.f, 0.f, 0.f, 0.f);
    if (has1) {
        float4 v1 = hn[64 + lane];
        a1 = make_float4(v1.x * s2, v1.y * s2, v1.z * s2, v1.w * s2);
    }
    int e1 = rowptr[n + 1];
    for (int e = rowptr[n]; e < e1; ++e) {
        int s = csr[e];
        float w = dinv[s] * di;
        const float4* hs = (const float4*)(h + (size_t)s * 320);
        float4 u0 = hs[lane];
        a0.x = fmaf(u0.x, w, a0.x); a0.y = fmaf(u0.y, w, a0.y);
        a0.z = fmaf(u0.z, w, a0.z); a0.w = fmaf(u0.w, w, a0.w);
        if (has1) {
            float4 u1 = hs[64 + lane];
            a1.x = fmaf(u1.x, w, a1.x); a1.y = fmaf(u1.y, w, a1.y);
            a1.z = fmaf(u1.z, w, a1.z); a1.w = fmaf(u1.w, w, a1.w);
        }
    }
    const float4* b4 = (const float4*)bias;
    float4* on = (float4*)(out + (size_t)n * 320);
    float4 bb = b4[lane];
    on[lane] = make_float4(a0.x + bb.x, a0.y + bb.y, a0.z + bb.z, a0.w + bb.w);
    if (has1) {
        float4 bb1 = b4[64 + lane];
        on[64 + lane] = make_float4(a1.x + bb1.x, a1.y + bb1.y, a1.z + bb1.z, a1.w + bb1.w);
    }
}

// ---------------- SAGE mean aggregation (float4) ----------------
template <int STR, int CH>
__global__ __launch_bounds__(256) void k_sage4(const float* __restrict__ x,
                                               const int* __restrict__ rowptr,
                                               const int* __restrict__ csr,
                                               const int* __restrict__ indeg,
                                               float* __restrict__ mean) {
    constexpr int NI = (CH + 63) / 64;
    int lane = threadIdx.x & 63;
    int n = blockIdx.x * 4 + (threadIdx.x >> 6);
    float4 acc[NI];
#pragma unroll
    for (int j = 0; j < NI; ++j) acc[j] = make_float4(0.f, 0.f, 0.f, 0.f);
    int e1 = rowptr[n + 1];
    for (int e = rowptr[n]; e < e1; ++e) {
        int s = csr[e];
        const float4* xs = (const float4*)(x + (size_t)s * STR);
#pragma unroll
        for (int j = 0; j < NI; ++j) {
            int ch = lane + 64 * j;
            if (ch < CH) {
                float4 u = xs[ch];
                acc[j].x += u.x; acc[j].y += u.y; acc[j].z += u.z; acc[j].w += u.w;
            }
        }
    }
    int cnt = indeg[n];
    float inv = 1.0f / (float)(cnt > 1 ? cnt : 1);
    float4* mn = (float4*)(mean + (size_t)n * STR);
#pragma unroll
    for (int j = 0; j < NI; ++j) {
        int ch = lane + 64 * j;
        if (ch < CH)
            mn[ch] = make_float4(acc[j].x * inv, acc[j].y * inv, acc[j].z * inv, acc[j].w * inv);
    }
}

template <int STR, int CH>
__global__ __launch_bounds__(256) void k_sage2(const float* __restrict__ x,
                                               const int* __restrict__ rowptr,
                                               const int* __restrict__ csr,
                                               const int* __restrict__ indeg,
                                               float* __restrict__ mean) {
    int lane = threadIdx.x & 63;
    int n = blockIdx.x * 4 + (threadIdx.x >> 6);
    float2 acc = make_float2(0.f, 0.f);
    bool act = lane < CH;
    int e1 = rowptr[n + 1];
    for (int e = rowptr[n]; e < e1; ++e) {
        int s = csr[e];
        if (act) {
            float2 u = ((const float2*)(x + (size_t)s * STR))[lane];
            acc.x += u.x; acc.y += u.y;
        }
    }
    int cnt = indeg[n];
    float inv = 1.0f / (float)(cnt > 1 ? cnt : 1);
    if (act)
        ((float2*)(mean + (size_t)n * STR))[lane] = make_float2(acc.x * inv, acc.y * inv);
}

// ---------------- batchnorm stats (leaky fused); 1024 blocks x 64 rows ----------------
template <int D, int STR>
__global__ __launch_bounds__(256) void k_bn_stats(const float* __restrict__ x,
                                                  float* __restrict__ stats) {
    constexpr int NC = (D + 255) / 256;
    int t = threadIdx.x;
    int r0 = blockIdx.x * 64;
    float s[NC], q[NC];
#pragma unroll
    for (int i = 0; i < NC; ++i) { s[i] = 0.f; q[i] = 0.f; }
#pragma unroll 4
    for (int r = r0; r < r0 + 64; ++r) {
        const float* row = x + (size_t)r * STR;
#pragma unroll
        for (int i = 0; i < NC; ++i) {
            int c = t + 256 * i;
            if (c < D) {
                float v = row[c];
                v = v >= 0.f ? v : 0.01f * v;
                s[i] += v;
                q[i] += v * v;
            }
        }
    }
#pragma unroll
    for (int i = 0; i < NC; ++i) {
        int c = t + 256 * i;
        if (c < D) {
            atomicAdd(&stats[c], s[i]);
            atomicAdd(&stats[512 + c], q[i]);
        }
    }
}

template <int STR>
__global__ __launch_bounds__(256) void k_bn_apply(float* __restrict__ x,
                                                  const float* __restrict__ stats) {
    const float invN = 1.0f / (float)NN;
    size_t total4 = (size_t)NN * STR / 4;
    size_t stride = (size_t)gridDim.x * 256;
    for (size_t i = (size_t)blockIdx.x * 256 + threadIdx.x; i < total4; i += stride) {
        int c = (int)((i * 4) % STR);
        float4 v = ((const float4*)x)[i];
        float4 m4 = *(const float4*)(stats + c);
        float4 q4 = *(const float4*)(stats + 512 + c);
        float4 o;
        {
            float mu = m4.x * invN, var = q4.x * invN - mu * mu;
            float u = v.x >= 0.f ? v.x : 0.01f * v.x;
            o.x = (u - mu) * rsqrtf(var + 1e-5f);
        }
        {
            float mu = m4.y * invN, var = q4.y * invN - mu * mu;
            float u = v.y >= 0.f ? v.y : 0.01f * v.y;
            o.y = (u - mu) * rsqrtf(var + 1e-5f);
        }
        {
            float mu = m4.z * invN, var = q4.z * invN - mu * mu;
            float u = v.z >= 0.f ? v.z : 0.01f * v.z;
            o.z = (u - mu) * rsqrtf(var + 1e-5f);
        }
        {
            float mu = m4.w * invN, var = q4.w * invN - mu * mu;
            float u = v.w >= 0.f ? v.w : 0.01f * v.w;
            o.w = (u - mu) * rsqrtf(var + 1e-5f);
        }
        ((float4*)x)[i] = o;
    }
}

// ---------------- pooling (input stride 64) ----------------
__global__ __launch_bounds__(256) void k_pool(const float* __restrict__ h,
                                              float* __restrict__ pooled) {
    int blk = blockIdx.x;
    int batch = blk >> 4, seg = blk & 15;
    int f = threadIdx.x & 63, g = threadIdx.x >> 6;
    size_t base = ((size_t)batch * 4096 + seg * 256 + g) * 64 + f;
    float acc = 0.f;
    for (int i = 0; i < 64; ++i) acc += h[base + (size_t)i * 256];
    atomicAdd(&pooled[batch * 64 + f], acc);
}

// ---------------- head ----------------
__global__ __launch_bounds__(256) void k_head(
    const float* __restrict__ gender, const float* __restrict__ age,
    const float* __restrict__ handed, const float* __restrict__ Wq,
    const float* __restrict__ bq, const float* __restrict__ Wk,
    const float* __restrict__ bk, const float* __restrict__ Wv,
    const float* __restrict__ bv, const float* __restrict__ Wfc,
    const float* __restrict__ bfc, const float* __restrict__ Wf1,
    const float* __restrict__ bf1, const float* __restrict__ Wf2,
    const float* __restrict__ bf2, const float* __restrict__ Wf3,
    const float* __restrict__ bf3, const float* __restrict__ pooled,
    float* __restrict__ dout) {
    __shared__ float plug[BS_][8];
    __shared__ float qs[BS_][32], ks[BS_][32], vs[BS_][32];
    __shared__ float gum[256];
    __shared__ float x32[BS_][32];
    __shared__ float px[BS_][4];
    __shared__ float embs[BS_][54];
    __shared__ float t1[BS_][32];
    __shared__ float t2[BS_][16];
    int t = threadIdx.x;

    if (t < 128) {
        int b = t >> 3, c = t & 7;
        float v;
        if (c < 2) v = gender[b * 2 + c];
        else if (c == 2) v = age[b];
        else v = handed[b * 5 + (c - 3)];
        plug[b][c] = v;
    }
    {
        u32 lane = (u32)(t & 127);
        u32 a = lane, b2 = lane + 128u;
        threefry_0_42(a, b2);
        u32 bits = (t < 128) ? a : b2;
        float u = __uint_as_float((bits >> 9) | 0x3f800000u) - 1.0f;
        const float mn = 1e-9f;
        u = u * (1.0f - mn) + mn;
        u = fmaxf(mn, u);
        gum[t] = -logf(-logf(u));
    }
    __syncthreads();
    for (int idx = t; idx < 512; idx += 256) {
        int b = idx >> 5, c = idx & 31;
        float aq = bq[c], ak = bk[c], av = bv[c];
#pragma unroll
        for (int i = 0; i < 8; ++i) {
            float p = plug[b][i];
            aq = fmaf(p, Wq[i * 32 + c], aq);
            ak = fmaf(p, Wk[i * 32 + c], ak);
            av = fmaf(p, Wv[i * 32 + c], av);
        }
        qs[b][c] = aq; ks[b][c] = ak; vs[b][c] = av;
    }
    __syncthreads();
    if (t < 64) {
        int b = t >> 2, h = t & 3;
        const float isq = 0.35355339059327373f;
        const float sq = 2.8284271247461903f;
        float sc[4];
#pragma unroll
        for (int j = 0; j < 4; ++j) {
            float d = 0.f;
#pragma unroll
            for (int dd = 0; dd < 8; ++dd) d = fmaf(qs[b][h * 8 + dd], ks[b][j * 8 + dd], d);
            sc[j] = d * isq + gum[b * 16 + h * 4 + j];
        }
        float m = fmaxf(fmaxf(sc[0], sc[1]), fmaxf(sc[2], sc[3]));
        float e0 = expf(sc[0] - m), e1 = expf(sc[1] - m), e2 = expf(sc[2] - m), e3 = expf(sc[3] - m);
        float sum = e0 + e1 + e2 + e3;
        float a0 = e0 / sum * sq, a1 = e1 / sum * sq, a2 = e2 / sum * sq, a3 = e3 / sum * sq;
#pragma unroll
        for (int dd = 0; dd < 8; ++dd) {
            float o = a0 * vs[b][0 * 8 + dd] + a1 * vs[b][1 * 8 + dd] +
                      a2 * vs[b][2 * 8 + dd] + a3 * vs[b][3 * 8 + dd];
            x32[b][h * 8 + dd] = o;
        }
    }
    __syncthreads();
    if (t < 64) {
        int b = t >> 2, n = t & 3;
        float a = bfc[n];
#pragma unroll
        for (int m = 0; m < 32; ++m) a = fmaf(x32[b][m], Wfc[m * 4 + n], a);
        px[b][n] = a;
    }
    __syncthreads();
    for (int idx = t; idx < BS_ * 54; idx += 256) {
        int b = idx / 54, c = idx % 54;
        float v = (c < 50) ? pooled[b * 64 + c] : px[b][c - 50];
        embs[b][c] = v;
        dout[16 + idx] = v;
    }
    __syncthreads();
    for (int idx = t; idx < 512; idx += 256) {
        int b = idx >> 5, c = idx & 31;
        float a = bf1[c];
#pragma unroll
        for (int k = 0; k < 54; ++k) a = fmaf(embs[b][k], Wf1[k * 32 + c], a);
        t1[b][c] = a;
    }
    __syncthreads();
    {
        int b = t >> 4, c = t & 15;
        float a = bf2[c];
#pragma unroll
        for (int k = 0; k < 32; ++k) a = fmaf(t1[b][k], Wf2[k * 16 + c], a);
        t2[b][c] = a;
    }
    __syncthreads();
    if (t < 16) {
        float a = bf3[0];
#pragma unroll
        for (int k = 0; k < 16; ++k) a = fmaf(t2[t][k], Wf3[k], a);
        dout[t] = a;
    }
}

// ---------------- launcher ----------------
extern "C" void kernel_launch(void* const* d_in, const int* in_sizes, int n_in,
                              void* d_out, int out_size, void* d_ws, size_t ws_size,
                              hipStream_t stream) {
    const float* x      = (const float*)d_in[0];
    const int*   ei     = (const int*)d_in[1];
    const float* gender = (const float*)d_in[2];
    const float* age    = (const float*)d_in[3];
    const float* handed = (const float*)d_in[4];
    const float* W1  = (const float*)d_in[5];
    const float* b1  = (const float*)d_in[6];
    const float* Wl2 = (const float*)d_in[7];
    const float* Wr2 = (const float*)d_in[8];
    const float* b2  = (const float*)d_in[9];
    const float* Wl3 = (const float*)d_in[10];
    const float* Wr3 = (const float*)d_in[11];
    const float* b3  = (const float*)d_in[12];
    const float* Wl4 = (const float*)d_in[13];
    const float* Wr4 = (const float*)d_in[14];
    const float* b4  = (const float*)d_in[15];
    const float* Wq  = (const float*)d_in[16];
    const float* bq  = (const float*)d_in[17];
    const float* Wk  = (const float*)d_in[18];
    const float* bk  = (const float*)d_in[19];
    const float* Wv  = (const float*)d_in[20];
    const float* bv  = (const float*)d_in[21];
    const float* Wfc = (const float*)d_in[22];
    const float* bfc = (const float*)d_in[23];
    const float* Wf1 = (const float*)d_in[24];
    const float* bf1 = (const float*)d_in[25];
    const float* Wf2 = (const float*)d_in[26];
    const float* bf2 = (const float*)d_in[27];
    const float* Wf3 = (const float*)d_in[28];
    const float* bf3 = (const float*)d_in[29];

    const int* srcp = ei;
    const int* dstp = ei + EE;

    char* wsb = (char*)d_ws;
    size_t off = 0;
    auto alloc = [&](size_t bytes) -> char* {
        char* p = wsb + off;
        off += (bytes + 255) & ~(size_t)255;
        return p;
    };
    float* P = (float*)alloc((size_t)NN * 320 * 4);
    float* Q = (float*)alloc((size_t)NN * 320 * 4);
    float* R = (float*)alloc((size_t)NN * 192 * 4);
    int* indeg  = (int*)alloc((size_t)NN * 4);
    int* rowptr = (int*)alloc((size_t)(NN + 1) * 4);
    int* cursor = (int*)alloc((size_t)(NN + 1) * 4);
    int* csr    = (int*)alloc((size_t)EE * 4);
    float* dinv = (float*)alloc((size_t)NN * 4);
    float* stats  = (float*)alloc(1024 * 4);
    float* pooled = (float*)alloc(16 * 64 * 4);
    u16* W1th  = (u16*)alloc((size_t)384 * 640 * 2);
    u16* W1tl  = (u16*)alloc((size_t)384 * 640 * 2);
    u16* Wr2th = (u16*)alloc((size_t)256 * 320 * 2);
    u16* Wr2tl = (u16*)alloc((size_t)256 * 320 * 2);
    u16* Wl2th = (u16*)alloc((size_t)256 * 320 * 2);
    u16* Wl2tl = (u16*)alloc((size_t)256 * 320 * 2);
    u16* Wr3th = (u16*)alloc((size_t)128 * 192 * 2);
    u16* Wr3tl = (u16*)alloc((size_t)128 * 192 * 2);
    u16* Wl3th = (u16*)alloc((size_t)128 * 192 * 2);
    u16* Wl3tl = (u16*)alloc((size_t)128 * 192 * 2);
    u16* Wr4th = (u16*)alloc((size_t)128 * 128 * 2);
    u16* Wr4tl = (u16*)alloc((size_t)128 * 128 * 2);
    u16* Wl4th = (u16*)alloc((size_t)128 * 128 * 2);
    u16* Wl4tl = (u16*)alloc((size_t)128 * 128 * 2);
    float* dout = (float*)d_out;

    // graph preprocessing
    hipMemsetAsync(indeg, 0, (size_t)NN * 4, stream);
    k_indeg<<<EE / 256, 256, 0, stream>>>(dstp, indeg);
    k_scan<<<1, 256, 0, stream>>>(indeg, rowptr, cursor);
    k_fill<<<EE / 256, 256, 0, stream>>>(srcp, dstp, cursor, csr);
    k_dinv<<<NN / 256, 256, 0, stream>>>(indeg, dinv);

    // weight splits
    k_wsplit<<<(384 * 640 + 255) / 256, 256, 0, stream>>>(W1, 640, 320, 640, 384, W1th, W1tl);
    k_wsplit<<<(256 * 320 + 255) / 256, 256, 0, stream>>>(Wr2, 320, 180, 320, 256, Wr2th, Wr2tl);
    k_wsplit<<<(256 * 320 + 255) / 256, 256, 0, stream>>>(Wl2, 320, 180, 320, 256, Wl2th, Wl2tl);
    k_wsplit<<<(128 * 192 + 255) / 256, 256, 0, stream>>>(Wr3, 180, 90, 192, 128, Wr3th, Wr3tl);
    k_wsplit<<<(128 * 192 + 255) / 256, 256, 0, stream>>>(Wl3, 180, 90, 192, 128, Wl3th, Wl3tl);
    k_wsplit<<<(128 * 128 + 255) / 256, 256, 0, stream>>>(Wr4, 90, 50, 128, 128, Wr4th, Wr4tl);
    k_wsplit<<<(128 * 128 + 255) / 256, 256, 0, stream>>>(Wl4, 90, 50, 128, 128, Wl4th, Wl4tl);

    // layer 1: GCN (640 -> 320)
    k_gemm_mfma<false><<<dim3(1024, 3), 256, 0, stream>>>(
        x, W1th, W1tl, 640, 640, nullptr, nullptr, nullptr, 0, 0, nullptr, P, 320, 320);
    k_gcn_agg320<<<NN / 4, 256, 0, stream>>>(P, rowptr, csr, dinv, b1, Q);
    hipMemsetAsync(stats, 0, 4096, stream);
    k_bn_stats<320, 320><<<1024, 256, 0, stream>>>(Q, stats);
    k_bn_apply<320><<<2048, 256, 0, stream>>>(Q, stats);

    // layer 2: SAGE (320 -> 180, stride 192)
    k_sage4<320, 80><<<NN / 4, 256, 0, stream>>>(Q, rowptr, csr, indeg, P);
    k_gemm_mfma<true><<<dim3(1024, 2), 256, 0, stream>>>(
        Q, Wr2th, Wr2tl, 320, 320, P, Wl2th, Wl2tl, 320, 320, b2, R, 180, 192);
    hipMemsetAsync(stats, 0, 4096, stream);
    k_bn_stats<180, 192><<<1024, 256, 0, stream>>>(R, stats);
    k_bn_apply<192><<<2048, 256, 0, stream>>>(R, stats);

    // layer 3: SAGE (180 -> 90, stride 128)
    k_sage4<192, 45><<<NN / 4, 256, 0, stream>>>(R, rowptr, csr, indeg, Q);
    k_gemm_mfma<true><<<dim3(1024, 1), 256, 0, stream>>>(
        R, Wr3th, Wr3tl, 192, 192, Q, Wl3th, Wl3tl, 192, 192, b3, P, 90, 128);
    hipMemsetAsync(stats, 0, 4096, stream);
    k_bn_stats<90, 128><<<1024, 256, 0, stream>>>(P, stats);
    k_bn_apply<128><<<2048, 256, 0, stream>>>(P, stats);

    // layer 4: SAGE (90 -> 50, stride 64)
    k_sage2<128, 45><<<NN / 4, 256, 0, stream>>>(P, rowptr, csr, indeg, R);
    k_gemm_mfma<true><<<dim3(1024, 1), 256, 0, stream>>>(
        P, Wr4th, Wr4tl, 128, 128, R, Wl4th, Wl4tl, 128, 128, b4, Q, 50, 64);
    hipMemsetAsync(stats, 0, 4096, stream);
    k_bn_stats<50, 64><<<1024, 256, 0, stream>>>(Q, stats);
    k_bn_apply<64><<<2048, 256, 0, stream>>>(Q, stats);

    // pooling + head
    hipMemsetAsync(pooled, 0, 16 * 64 * 4, stream);
    k_pool<<<256, 256, 0, stream>>>(Q, pooled);
    k_head<<<1, 256, 0, stream>>>(gender, age, handed, Wq, bq, Wk, bk, Wv, bv,
                                  Wfc, bfc, Wf1, bf1, Wf2, bf2, Wf3, bf3, pooled, dout);
}

// Round 5
// 1129.315 us; speedup vs baseline: 2.3406x; 1.1680x over previous
//
#include <hip/hip_runtime.h>
#include <cstdint>

#define NN 65536
#define EE 524288
#define BS_ 16

typedef unsigned short u16;
typedef unsigned int u32;
typedef __attribute__((ext_vector_type(8))) short short8v;
typedef __attribute__((ext_vector_type(4))) float f32x4;

// ---------------- bf16 split helpers ----------------
__device__ __forceinline__ u16 f2bf(float f) {
    u32 u = __float_as_uint(f);
    u32 r = (u + 0x7fffu + ((u >> 16) & 1u)) >> 16;
    return (u16)r;
}
__device__ __forceinline__ float bff(u16 h) {
    return __uint_as_float(((u32)h) << 16);
}

// leaky_relu + batchnorm affine from raw sums
__device__ __forceinline__ float bnleaky(float v, float s, float q) {
    const float invN = 1.0f / 65536.0f;
    float mu = s * invN;
    float var = q * invN - mu * mu;
    float u = v >= 0.f ? v : 0.01f * v;
    return (u - mu) * rsqrtf(var + 1e-5f);
}

// ---------------- threefry2x32 (JAX-compatible, key = (0,42)) ----------------
__device__ __forceinline__ u32 rotl32(u32 x, int d) {
    return (x << d) | (x >> (32 - d));
}
__device__ __forceinline__ void threefry_0_42(u32& x0, u32& x1) {
    const u32 ks0 = 0u, ks1 = 42u, ks2 = 0u ^ 42u ^ 0x1BD11BDAu;
    x0 += ks0; x1 += ks1;
#define RND(r) { x0 += x1; x1 = rotl32(x1, r); x1 ^= x0; }
    RND(13) RND(15) RND(26) RND(6)  x0 += ks1; x1 += ks2 + 1u;
    RND(17) RND(29) RND(16) RND(24) x0 += ks2; x1 += ks0 + 2u;
    RND(13) RND(15) RND(26) RND(6)  x0 += ks0; x1 += ks1 + 3u;
    RND(17) RND(29) RND(16) RND(24) x0 += ks1; x1 += ks2 + 4u;
    RND(13) RND(15) RND(26) RND(6)  x0 += ks2; x1 += ks0 + 5u;
#undef RND
}

// ---------------- graph preprocessing ----------------
__global__ void k_indeg(const int* __restrict__ dst, int* __restrict__ indeg) {
    int e = blockIdx.x * 256 + threadIdx.x;
    if (e < EE) atomicAdd(&indeg[dst[e]], 1);
}

__global__ void k_scan(const int* __restrict__ indeg, int* __restrict__ rowptr,
                       int* __restrict__ cursor) {
    __shared__ int psum[256];
    int t = threadIdx.x;
    int base = t * 256;
    int s = 0;
    for (int i = 0; i < 256; ++i) s += indeg[base + i];
    psum[t] = s;
    __syncthreads();
    for (int off = 1; off < 256; off <<= 1) {
        int v = (t >= off) ? psum[t - off] : 0;
        __syncthreads();
        psum[t] += v;
        __syncthreads();
    }
    int run = (t == 0) ? 0 : psum[t - 1];
    for (int i = 0; i < 256; ++i) {
        rowptr[base + i] = run;
        cursor[base + i] = run;
        run += indeg[base + i];
    }
    if (t == 255) rowptr[NN] = run;
}

__global__ void k_fill(const int* __restrict__ src, const int* __restrict__ dst,
                       int* __restrict__ cursor, int* __restrict__ csr) {
    int e = blockIdx.x * 256 + threadIdx.x;
    if (e < EE) {
        int d = dst[e];
        int p = atomicAdd(&cursor[d], 1);
        csr[p] = src[e];
    }
}

__global__ void k_dinv(const int* __restrict__ indeg, float* __restrict__ dinv) {
    int i = blockIdx.x * 256 + threadIdx.x;
    if (i < NN) dinv[i] = rsqrtf((float)indeg[i] + 1.0f);
}

// ---------------- stacked weight transpose + hi/lo bf16 split ----------------
// rows [0,CS): Wr (out1 cols); rows [CS,NPW): Wl (out2 cols) or zero
__global__ void k_wsplit2(const float* __restrict__ Wr, const float* __restrict__ Wlsrc,
                          int K, int N, int KP, int CS, int NPW,
                          u16* __restrict__ Wh, u16* __restrict__ Wl) {
    int idx = blockIdx.x * 256 + threadIdx.x;
    if (idx >= NPW * KP) return;
    int n = idx / KP, k = idx % KP;
    float v = 0.f;
    if (n < CS) {
        if (n < N && k < K) v = Wr[(size_t)k * N + n];
    } else {
        int n2 = n - CS;
        if (Wlsrc != nullptr && n2 < N && k < K) v = Wlsrc[(size_t)k * N + n2];
    }
    u16 h = f2bf(v);
    u16 l = f2bf(v - bff(h));
    Wh[idx] = h;
    Wl[idx] = l;
}

// ---------------- split-bf16 MFMA GEMM, fused leaky+BN on A, dual output ----------------
// O1[M x CS] = bn(A) @ W[rows 0..CS)  (+bias for col<N)
// O2[M x CS] = bn(A) @ W[rows CS..2CS)   (if O2 != null)
template <bool HASB, bool HASBN>
__global__ __launch_bounds__(256, 2) void k_gemm_mfma(
    const float* __restrict__ A, const u16* __restrict__ Wgh, const u16* __restrict__ Wgl,
    int KP, int lda, const float* __restrict__ bns,
    const float* __restrict__ bias, float* __restrict__ O1, float* __restrict__ O2,
    int N, int CS) {
    __shared__ u16 Ah[64][72];
    __shared__ u16 Al[64][72];
    __shared__ u16 Wh[128][72];
    __shared__ u16 Wl[128][72];

    const int t = threadIdx.x;
    const int bm = blockIdx.x * 64;
    const int bn = blockIdx.y * 128;
    const int lane = t & 63;
    const int wid = t >> 6;
    const int wr = wid >> 1, wc = wid & 1;

    f32x4 acc[2][4];
#pragma unroll
    for (int m = 0; m < 2; ++m)
#pragma unroll
        for (int n = 0; n < 4; ++n) acc[m][n] = (f32x4){0.f, 0.f, 0.f, 0.f};

    const int sr = t >> 4;
    const int sc4 = (t & 15) * 4;

    for (int k0 = 0; k0 < KP; k0 += 64) {
        float4 s4, q4;
        if (HASBN) {
            s4 = *(const float4*)(bns + k0 + sc4);
            q4 = *(const float4*)(bns + 512 + k0 + sc4);
        }
#pragma unroll
        for (int p = 0; p < 4; ++p) {
            int rr = sr + 16 * p;
            const float4 v = *(const float4*)(A + (size_t)(bm + rr) * lda + k0 + sc4);
            float vx = v.x, vy = v.y, vz = v.z, vw = v.w;
            if (HASBN) {
                vx = bnleaky(vx, s4.x, q4.x);
                vy = bnleaky(vy, s4.y, q4.y);
                vz = bnleaky(vz, s4.z, q4.z);
                vw = bnleaky(vw, s4.w, q4.w);
            }
            u16 h0 = f2bf(vx), h1 = f2bf(vy), h2 = f2bf(vz), h3 = f2bf(vw);
            u16 l0 = f2bf(vx - bff(h0)), l1 = f2bf(vy - bff(h1));
            u16 l2 = f2bf(vz - bff(h2)), l3 = f2bf(vw - bff(h3));
            uint2 hh, ll;
            hh.x = (u32)h0 | ((u32)h1 << 16); hh.y = (u32)h2 | ((u32)h3 << 16);
            ll.x = (u32)l0 | ((u32)l1 << 16); ll.y = (u32)l2 | ((u32)l3 << 16);
            *(uint2*)&Ah[rr][sc4] = hh;
            *(uint2*)&Al[rr][sc4] = ll;
        }
#pragma unroll
        for (int p = 0; p < 8; ++p) {
            int nn = sr + 16 * p;
            size_t go = (size_t)(bn + nn) * KP + k0 + sc4;
            *(uint2*)&Wh[nn][sc4] = *(const uint2*)(Wgh + go);
            *(uint2*)&Wl[nn][sc4] = *(const uint2*)(Wgl + go);
        }
        __syncthreads();
        const int fr = lane & 15;
        const int kg = (lane >> 4) * 8;
#pragma unroll
        for (int kk = 0; kk < 64; kk += 32) {
            short8v a_h[2], a_l[2], w_h[4], w_l[4];
#pragma unroll
            for (int m = 0; m < 2; ++m) {
                a_h[m] = *(const short8v*)&Ah[wr * 32 + m * 16 + fr][kk + kg];
                a_l[m] = *(const short8v*)&Al[wr * 32 + m * 16 + fr][kk + kg];
            }
#pragma unroll
            for (int n = 0; n < 4; ++n) {
                w_h[n] = *(const short8v*)&Wh[wc * 64 + n * 16 + fr][kk + kg];
                w_l[n] = *(const short8v*)&Wl[wc * 64 + n * 16 + fr][kk + kg];
            }
#pragma unroll
            for (int m = 0; m < 2; ++m)
#pragma unroll
                for (int n = 0; n < 4; ++n) {
                    acc[m][n] = __builtin_amdgcn_mfma_f32_16x16x32_bf16(a_h[m], w_h[n], acc[m][n], 0, 0, 0);
                    acc[m][n] = __builtin_amdgcn_mfma_f32_16x16x32_bf16(a_h[m], w_l[n], acc[m][n], 0, 0, 0);
                    acc[m][n] = __builtin_amdgcn_mfma_f32_16x16x32_bf16(a_l[m], w_h[n], acc[m][n], 0, 0, 0);
                }
        }
        __syncthreads();
    }
    const int fr = lane & 15, fq = lane >> 4;
#pragma unroll
    for (int m = 0; m < 2; ++m) {
        int row = bm + wr * 32 + m * 16 + fq * 4;
#pragma unroll
        for (int n = 0; n < 4; ++n) {
            int col = bn + wc * 64 + n * 16 + fr;
            if (col < CS) {
                float b = (HASB && col < N) ? bias[col] : 0.f;
#pragma unroll
                for (int e = 0; e < 4; ++e)
                    O1[(size_t)(row + e) * CS + col] = acc[m][n][e] + b;
            } else if (O2 != nullptr) {
                int c2 = col - CS;
#pragma unroll
                for (int e = 0; e < 4; ++e)
                    O2[(size_t)(row + e) * CS + c2] = acc[m][n][e];
            }
        }
    }
}

// ---------------- GCN aggregation, D=320 (float4, edge unroll-4) ----------------
__global__ __launch_bounds__(256) void k_gcn_agg320(const float* __restrict__ h,
                                                    const int* __restrict__ rowptr,
                                                    const int* __restrict__ csr,
                                                    const float* __restrict__ dinv,
                                                    const float* __restrict__ bias,
                                                    float* __restrict__ out) {
    int lane = threadIdx.x & 63;
    int n = blockIdx.x * 4 + (threadIdx.x >> 6);
    bool has1 = lane < 16;
    float di = dinv[n];
    float s2 = di * di;
    const float4* hn = (const float4*)(h + (size_t)n * 320);
    float4 v0 = hn[lane];
    float4 a0 = make_float4(v0.x * s2, v0.y * s2, v0.z * s2, v0.w * s2);
    float4 a1 = make_float4(0.f, 0.f, 0.f, 0.f);
    if (has1) {
        float4 v1 = hn[64 + lane];
        a1 = make_float4(v1.x * s2, v1.y * s2, v1.z * s2, v1.w * s2);
    }
    int e = rowptr[n], e1 = rowptr[n + 1];
    for (; e + 4 <= e1; e += 4) {
        int s0 = csr[e], s1 = csr[e + 1], s2i = csr[e + 2], s3 = csr[e + 3];
        float w0 = dinv[s0] * di, w1 = dinv[s1] * di, w2 = dinv[s2i] * di, w3 = dinv[s3] * di;
        const float4* p0 = (const float4*)(h + (size_t)s0 * 320);
        const float4* p1 = (const float4*)(h + (size_t)s1 * 320);
        const float4* p2 = (const float4*)(h + (size_t)s2i * 320);
        const float4* p3 = (const float4*)(h + (size_t)s3 * 320);
        float4 u0 = p0[lane], u1 = p1[lane], u2 = p2[lane], u3 = p3[lane];
        a0.x += u0.x * w0 + u1.x * w1 + u2.x * w2 + u3.x * w3;
        a0.y += u0.y * w0 + u1.y * w1 + u2.y * w2 + u3.y * w3;
        a0.z += u0.z * w0 + u1.z * w1 + u2.z * w2 + u3.z * w3;
        a0.w += u0.w * w0 + u1.w * w1 + u2.w * w2 + u3.w * w3;
        if (has1) {
            float4 x0 = p0[64 + lane], x1 = p1[64 + lane], x2 = p2[64 + lane], x3 = p3[64 + lane];
            a1.x += x0.x * w0 + x1.x * w1 + x2.x * w2 + x3.x * w3;
            a1.y += x0.y * w0 + x1.y * w1 + x2.y * w2 + x3.y * w3;
            a1.z += x0.z * w0 + x1.z * w1 + x2.z * w2 + x3.z * w3;
            a1.w += x0.w * w0 + x1.w * w1 + x2.w * w2 + x3.w * w3;
        }
    }
    for (; e < e1; ++e) {
        int s = csr[e];
        float w = dinv[s] * di;
        const float4* hs = (const float4*)(h + (size_t)s * 320);
        float4 u0 = hs[lane];
        a0.x = fmaf(u0.x, w, a0.x); a0.y = fmaf(u0.y, w, a0.y);
        a0.z = fmaf(u0.z, w, a0.z); a0.w = fmaf(u0.w, w, a0.w);
        if (has1) {
            float4 u1 = hs[64 + lane];
            a1.x = fmaf(u1.x, w, a1.x); a1.y = fmaf(u1.y, w, a1.y);
            a1.z = fmaf(u1.z, w, a1.z); a1.w = fmaf(u1.w, w, a1.w);
        }
    }
    const float4* b4 = (const float4*)bias;
    float4* on = (float4*)(out + (size_t)n * 320);
    float4 bb = b4[lane];
    on[lane] = make_float4(a0.x + bb.x, a0.y + bb.y, a0.z + bb.z, a0.w + bb.w);
    if (has1) {
        float4 bb1 = b4[64 + lane];
        on[64 + lane] = make_float4(a1.x + bb1.x, a1.y + bb1.y, a1.z + bb1.z, a1.w + bb1.w);
    }
}

// ---------------- C[n] += mean-gather(T[s]); stride = 4*CH floats ----------------
template <int CH, int LOG_NPW>
__global__ __launch_bounds__(256) void k_agg_add(const float* __restrict__ T,
                                                 const int* __restrict__ rowptr,
                                                 const int* __restrict__ csr,
                                                 const int* __restrict__ indeg,
                                                 float* __restrict__ C) {
    constexpr int NPW = 1 << LOG_NPW;
    constexpr int LPN = 64 >> LOG_NPW;
    constexpr int SC = CH * 4;
    int lane = threadIdx.x & 63;
    int sub = lane / LPN;
    int ch = lane & (LPN - 1);
    int n = (blockIdx.x * 4 + (threadIdx.x >> 6)) * NPW + sub;
    bool act = ch < CH;
    float4 acc = make_float4(0.f, 0.f, 0.f, 0.f);
    int e = rowptr[n], e1 = rowptr[n + 1];
    for (; e + 4 <= e1; e += 4) {
        int s0 = csr[e], s1 = csr[e + 1], s2 = csr[e + 2], s3 = csr[e + 3];
        if (act) {
            float4 u0 = *(const float4*)(T + (size_t)s0 * SC + ch * 4);
            float4 u1 = *(const float4*)(T + (size_t)s1 * SC + ch * 4);
            float4 u2 = *(const float4*)(T + (size_t)s2 * SC + ch * 4);
            float4 u3 = *(const float4*)(T + (size_t)s3 * SC + ch * 4);
            acc.x += (u0.x + u1.x) + (u2.x + u3.x);
            acc.y += (u0.y + u1.y) + (u2.y + u3.y);
            acc.z += (u0.z + u1.z) + (u2.z + u3.z);
            acc.w += (u0.w + u1.w) + (u2.w + u3.w);
        }
    }
    for (; e < e1; ++e) {
        int s = csr[e];
        if (act) {
            float4 u = *(const float4*)(T + (size_t)s * SC + ch * 4);
            acc.x += u.x; acc.y += u.y; acc.z += u.z; acc.w += u.w;
        }
    }
    int cnt = indeg[n];
    float inv = 1.0f / (float)(cnt > 1 ? cnt : 1);
    if (act) {
        float4* cp = (float4*)(C + (size_t)n * SC + ch * 4);
        float4 c = *cp;
        c.x = fmaf(acc.x, inv, c.x);
        c.y = fmaf(acc.y, inv, c.y);
        c.z = fmaf(acc.z, inv, c.z);
        c.w = fmaf(acc.w, inv, c.w);
        *cp = c;
    }
}

// ---------------- batchnorm stats (leaky fused); 1024 blocks x 64 rows ----------------
template <int D, int STR>
__global__ __launch_bounds__(256) void k_bn_stats(const float* __restrict__ x,
                                                  float* __restrict__ stats) {
    constexpr int NC = (D + 255) / 256;
    int t = threadIdx.x;
    int r0 = blockIdx.x * 64;
    float s[NC], q[NC];
#pragma unroll
    for (int i = 0; i < NC; ++i) { s[i] = 0.f; q[i] = 0.f; }
#pragma unroll 4
    for (int r = r0; r < r0 + 64; ++r) {
        const float* row = x + (size_t)r * STR;
#pragma unroll
        for (int i = 0; i < NC; ++i) {
            int c = t + 256 * i;
            if (c < D) {
                float v = row[c];
                v = v >= 0.f ? v : 0.01f * v;
                s[i] += v;
                q[i] += v * v;
            }
        }
    }
#pragma unroll
    for (int i = 0; i < NC; ++i) {
        int c = t + 256 * i;
        if (c < D) {
            atomicAdd(&stats[c], s[i]);
            atomicAdd(&stats[512 + c], q[i]);
        }
    }
}

template <int STR>
__global__ __launch_bounds__(256) void k_bn_apply(float* __restrict__ x,
                                                  const float* __restrict__ stats) {
    const float invN = 1.0f / (float)NN;
    size_t total4 = (size_t)NN * STR / 4;
    size_t stride = (size_t)gridDim.x * 256;
    for (size_t i = (size_t)blockIdx.x * 256 + threadIdx.x; i < total4; i += stride) {
        int c = (int)((i * 4) % STR);
        float4 v = ((const float4*)x)[i];
        float4 m4 = *(const float4*)(stats + c);
        float4 q4 = *(const float4*)(stats + 512 + c);
        float4 o;
        o.x = bnleaky(v.x, m4.x, q4.x);
        o.y = bnleaky(v.y, m4.y, q4.y);
        o.z = bnleaky(v.z, m4.z, q4.z);
        o.w = bnleaky(v.w, m4.w, q4.w);
        ((float4*)x)[i] = o;
    }
}

// ---------------- pooling (input stride 64) ----------------
__global__ __launch_bounds__(256) void k_pool(const float* __restrict__ h,
                                              float* __restrict__ pooled) {
    int blk = blockIdx.x;
    int batch = blk >> 4, seg = blk & 15;
    int f = threadIdx.x & 63, g = threadIdx.x >> 6;
    size_t base = ((size_t)batch * 4096 + seg * 256 + g) * 64 + f;
    float acc = 0.f;
    for (int i = 0; i < 64; ++i) acc += h[base + (size_t)i * 256];
    atomicAdd(&pooled[batch * 64 + f], acc);
}

// ---------------- head ----------------
__global__ __launch_bounds__(256) void k_head(
    const float* __restrict__ gender, const float* __restrict__ age,
    const float* __restrict__ handed, const float* __restrict__ Wq,
    const float* __restrict__ bq, const float* __restrict__ Wk,
    const float* __restrict__ bk, const float* __restrict__ Wv,
    const float* __restrict__ bv, const float* __restrict__ Wfc,
    const float* __restrict__ bfc, const float* __restrict__ Wf1,
    const float* __restrict__ bf1, const float* __restrict__ Wf2,
    const float* __restrict__ bf2, const float* __restrict__ Wf3,
    const float* __restrict__ bf3, const float* __restrict__ pooled,
    float* __restrict__ dout) {
    __shared__ float plug[BS_][8];
    __shared__ float qs[BS_][32], ks[BS_][32], vs[BS_][32];
    __shared__ float gum[256];
    __shared__ float x32[BS_][32];
    __shared__ float px[BS_][4];
    __shared__ float embs[BS_][54];
    __shared__ float t1[BS_][32];
    __shared__ float t2[BS_][16];
    int t = threadIdx.x;

    if (t < 128) {
        int b = t >> 3, c = t & 7;
        float v;
        if (c < 2) v = gender[b * 2 + c];
        else if (c == 2) v = age[b];
        else v = handed[b * 5 + (c - 3)];
        plug[b][c] = v;
    }
    {
        u32 lane = (u32)(t & 127);
        u32 a = lane, b2 = lane + 128u;
        threefry_0_42(a, b2);
        u32 bits = (t < 128) ? a : b2;
        float u = __uint_as_float((bits >> 9) | 0x3f800000u) - 1.0f;
        const float mn = 1e-9f;
        u = u * (1.0f - mn) + mn;
        u = fmaxf(mn, u);
        gum[t] = -logf(-logf(u));
    }
    __syncthreads();
    for (int idx = t; idx < 512; idx += 256) {
        int b = idx >> 5, c = idx & 31;
        float aq = bq[c], ak = bk[c], av = bv[c];
#pragma unroll
        for (int i = 0; i < 8; ++i) {
            float p = plug[b][i];
            aq = fmaf(p, Wq[i * 32 + c], aq);
            ak = fmaf(p, Wk[i * 32 + c], ak);
            av = fmaf(p, Wv[i * 32 + c], av);
        }
        qs[b][c] = aq; ks[b][c] = ak; vs[b][c] = av;
    }
    __syncthreads();
    if (t < 64) {
        int b = t >> 2, h = t & 3;
        const float isq = 0.35355339059327373f;
        const float sq = 2.8284271247461903f;
        float sc[4];
#pragma unroll
        for (int j = 0; j < 4; ++j) {
            float d = 0.f;
#pragma unroll
            for (int dd = 0; dd < 8; ++dd) d = fmaf(qs[b][h * 8 + dd], ks[b][j * 8 + dd], d);
            sc[j] = d * isq + gum[b * 16 + h * 4 + j];
        }
        float m = fmaxf(fmaxf(sc[0], sc[1]), fmaxf(sc[2], sc[3]));
        float e0 = expf(sc[0] - m), e1 = expf(sc[1] - m), e2 = expf(sc[2] - m), e3 = expf(sc[3] - m);
        float sum = e0 + e1 + e2 + e3;
        float a0 = e0 / sum * sq, a1 = e1 / sum * sq, a2 = e2 / sum * sq, a3 = e3 / sum * sq;
#pragma unroll
        for (int dd = 0; dd < 8; ++dd) {
            float o = a0 * vs[b][0 * 8 + dd] + a1 * vs[b][1 * 8 + dd] +
                      a2 * vs[b][2 * 8 + dd] + a3 * vs[b][3 * 8 + dd];
            x32[b][h * 8 + dd] = o;
        }
    }
    __syncthreads();
    if (t < 64) {
        int b = t >> 2, n = t & 3;
        float a = bfc[n];
#pragma unroll
        for (int m = 0; m < 32; ++m) a = fmaf(x32[b][m], Wfc[m * 4 + n], a);
        px[b][n] = a;
    }
    __syncthreads();
    for (int idx = t; idx < BS_ * 54; idx += 256) {
        int b = idx / 54, c = idx % 54;
        float v = (c < 50) ? pooled[b * 64 + c] : px[b][c - 50];
        embs[b][c] = v;
        dout[16 + idx] = v;
    }
    __syncthreads();
    for (int idx = t; idx < 512; idx += 256) {
        int b = idx >> 5, c = idx & 31;
        float a = bf1[c];
#pragma unroll
        for (int k = 0; k < 54; ++k) a = fmaf(embs[b][k], Wf1[k * 32 + c], a);
        t1[b][c] = a;
    }
    __syncthreads();
    {
        int b = t >> 4, c = t & 15;
        float a = bf2[c];
#pragma unroll
        for (int k = 0; k < 32; ++k) a = fmaf(t1[b][k], Wf2[k * 16 + c], a);
        t2[b][c] = a;
    }
    __syncthreads();
    if (t < 16) {
        float a = bf3[0];
#pragma unroll
        for (int k = 0; k < 16; ++k) a = fmaf(t2[t][k], Wf3[k], a);
        dout[t] = a;
    }
}

// ---------------- launcher ----------------
extern "C" void kernel_launch(void* const* d_in, const int* in_sizes, int n_in,
                              void* d_out, int out_size, void* d_ws, size_t ws_size,
                              hipStream_t stream) {
    const float* x      = (const float*)d_in[0];
    const int*   ei     = (const int*)d_in[1];
    const float* gender = (const float*)d_in[2];
    const float* age    = (const float*)d_in[3];
    const float* handed = (const float*)d_in[4];
    const float* W1  = (const float*)d_in[5];
    const float* b1  = (const float*)d_in[6];
    const float* Wl2 = (const float*)d_in[7];
    const float* Wr2 = (const float*)d_in[8];
    const float* b2  = (const float*)d_in[9];
    const float* Wl3 = (const float*)d_in[10];
    const float* Wr3 = (const float*)d_in[11];
    const float* b3  = (const float*)d_in[12];
    const float* Wl4 = (const float*)d_in[13];
    const float* Wr4 = (const float*)d_in[14];
    const float* b4  = (const float*)d_in[15];
    const float* Wq  = (const float*)d_in[16];
    const float* bq  = (const float*)d_in[17];
    const float* Wk  = (const float*)d_in[18];
    const float* bk  = (const float*)d_in[19];
    const float* Wv  = (const float*)d_in[20];
    const float* bv  = (const float*)d_in[21];
    const float* Wfc = (const float*)d_in[22];
    const float* bfc = (const float*)d_in[23];
    const float* Wf1 = (const float*)d_in[24];
    const float* bf1 = (const float*)d_in[25];
    const float* Wf2 = (const float*)d_in[26];
    const float* bf2 = (const float*)d_in[27];
    const float* Wf3 = (const float*)d_in[28];
    const float* bf3 = (const float*)d_in[29];

    const int* srcp = ei;
    const int* dstp = ei + EE;

    char* wsb = (char*)d_ws;
    size_t off = 0;
    auto alloc = [&](size_t bytes) -> char* {
        char* p = wsb + off;
        off += (bytes + 255) & ~(size_t)255;
        return p;
    };
    float* P = (float*)alloc((size_t)NN * 320 * 4);
    float* Q = (float*)alloc((size_t)NN * 320 * 4);
    float* R = (float*)alloc((size_t)NN * 192 * 4);
    float* T = (float*)alloc((size_t)NN * 192 * 4);
    int* indeg  = (int*)alloc((size_t)NN * 4);
    int* rowptr = (int*)alloc((size_t)(NN + 1) * 4);
    int* cursor = (int*)alloc((size_t)(NN + 1) * 4);
    int* csr    = (int*)alloc((size_t)EE * 4);
    float* dinv = (float*)alloc((size_t)NN * 4);
    float* stats  = (float*)alloc(4096 * 4);  // 4 regions x 1024
    float* pooled = (float*)alloc(16 * 64 * 4);
    // stacked weight splits: [NPW][KP] bf16 hi/lo
    u16* W1h = (u16*)alloc((size_t)384 * 640 * 2);
    u16* W1l = (u16*)alloc((size_t)384 * 640 * 2);
    u16* W2h = (u16*)alloc((size_t)384 * 320 * 2);
    u16* W2l = (u16*)alloc((size_t)384 * 320 * 2);
    u16* W3h = (u16*)alloc((size_t)256 * 192 * 2);
    u16* W3l = (u16*)alloc((size_t)256 * 192 * 2);
    u16* W4h = (u16*)alloc((size_t)128 * 128 * 2);
    u16* W4l = (u16*)alloc((size_t)128 * 128 * 2);
    float* dout = (float*)d_out;

    // graph preprocessing
    hipMemsetAsync(indeg, 0, (size_t)NN * 4, stream);
    hipMemsetAsync(stats, 0, 4096 * 4, stream);
    k_indeg<<<EE / 256, 256, 0, stream>>>(dstp, indeg);
    k_scan<<<1, 256, 0, stream>>>(indeg, rowptr, cursor);
    k_fill<<<EE / 256, 256, 0, stream>>>(srcp, dstp, cursor, csr);
    k_dinv<<<NN / 256, 256, 0, stream>>>(indeg, dinv);

    // weight splits (stacked [Wr | Wl])
    k_wsplit2<<<(384 * 640 + 255) / 256, 256, 0, stream>>>(W1, nullptr, 640, 320, 640, 320, 384, W1h, W1l);
    k_wsplit2<<<(384 * 320 + 255) / 256, 256, 0, stream>>>(Wr2, Wl2, 320, 180, 320, 192, 384, W2h, W2l);
    k_wsplit2<<<(256 * 192 + 255) / 256, 256, 0, stream>>>(Wr3, Wl3, 180, 90, 192, 128, 256, W3h, W3l);
    k_wsplit2<<<(128 * 128 + 255) / 256, 256, 0, stream>>>(Wr4, Wl4, 90, 50, 128, 64, 128, W4h, W4l);

    // layer 1: GCN (640 -> 320).  P = x @ W1 ; Q = gcn_agg(P) + b1 (raw, pre-BN)
    k_gemm_mfma<false, false><<<dim3(1024, 3), 256, 0, stream>>>(
        x, W1h, W1l, 640, 640, nullptr, nullptr, P, nullptr, 320, 320);
    k_gcn_agg320<<<NN / 4, 256, 0, stream>>>(P, rowptr, csr, dinv, b1, Q);
    k_bn_stats<320, 320><<<1024, 256, 0, stream>>>(Q, stats);

    // layer 2: SAGE (320 -> 180, stride 192).  [R | T] = bn(Q) @ [Wr2 | Wl2]; R += mean(T)
    k_gemm_mfma<true, true><<<dim3(1024, 3), 256, 0, stream>>>(
        Q, W2h, W2l, 320, 320, stats, b2, R, T, 180, 192);
    k_agg_add<48, 0><<<NN / 4, 256, 0, stream>>>(T, rowptr, csr, indeg, R);
    k_bn_stats<180, 192><<<1024, 256, 0, stream>>>(R, stats + 1024);

    // layer 3: SAGE (180 -> 90, stride 128).  [P | T] = bn(R) @ [Wr3 | Wl3]; P += mean(T)
    k_gemm_mfma<true, true><<<dim3(1024, 2), 256, 0, stream>>>(
        R, W3h, W3l, 192, 192, stats + 1024, b3, P, T, 90, 128);
    k_agg_add<32, 1><<<NN / 8, 256, 0, stream>>>(T, rowptr, csr, indeg, P);
    k_bn_stats<90, 128><<<1024, 256, 0, stream>>>(P, stats + 2048);

    // layer 4: SAGE (90 -> 50, stride 64).  [Q | T] = bn(P) @ [Wr4 | Wl4]; Q += mean(T)
    k_gemm_mfma<true, true><<<dim3(1024, 1), 256, 0, stream>>>(
        P, W4h, W4l, 128, 128, stats + 2048, b4, Q, T, 50, 64);
    k_agg_add<16, 2><<<NN / 16, 256, 0, stream>>>(T, rowptr, csr, indeg, Q);
    k_bn_stats<50, 64><<<1024, 256, 0, stream>>>(Q, stats + 3072);
    k_bn_apply<64><<<2048, 256, 0, stream>>>(Q, stats + 3072);

    // pooling + head
    hipMemsetAsync(pooled, 0, 16 * 64 * 4, stream);
    k_pool<<<256, 256, 0, stream>>>(Q, pooled);
    k_head<<<1, 256, 0, stream>>>(gender, age, handed, Wq, bq, Wk, bk, Wv, bv,
                                  Wfc, bfc, Wf1, bf1, Wf2, bf2, Wf3, bf3, pooled, dout);
}